// Round 7
// baseline (315.645 us; speedup 1.0000x reference)
//
#include <hip/hip_runtime.h>
#include <math.h>

// Problem constants
#define Bb  4
#define Ss  2048
#define Ee  1024
#define Hh  16
#define KVh 4
#define HD  64
#define RNK 8
#define CDd 64
#define NQ  8
#define NLn 2
#define NF  16          // 2*NQ
#define NC  32          // chunks over S
#define CT  (Ss/NC)     // 64 steps per chunk
#define BS  (Bb*Ss)     // 8192 rows
#define NCAT 1664       // 512 qa + 512 ka + 512 va + 64 ctx + 64 pad

typedef unsigned short ushort_t;
typedef __attribute__((ext_vector_type(8))) short short8;
typedef __attribute__((ext_vector_type(4))) float f32x4;
typedef __attribute__((ext_vector_type(4))) unsigned short u16x4;

__device__ __forceinline__ unsigned short f2bf(float f) {
    unsigned int u = __float_as_uint(f);
    unsigned int r = (u + 0x7FFFu + ((u >> 16) & 1u)) >> 16;
    return (unsigned short)r;
}
__device__ __forceinline__ float bf2f(unsigned short h) {
    return __uint_as_float(((unsigned int)h) << 16);
}

#define GLD16(gp, lp) \
    __builtin_amdgcn_global_load_lds((const __attribute__((address_space(1))) void*)(gp), \
                                     (__attribute__((address_space(3))) void*)(lp), 16, 0, 0)

// ---------------- cast f32 -> bf16, 8 elems/thread ----------------
__global__ __launch_bounds__(256)
void cast_f32_bf16(const float* __restrict__ in, ushort_t* __restrict__ outp, long n)
{
    long i = ((long)blockIdx.x * blockDim.x + threadIdx.x) * 8;
    if (i >= n) return;
    short8 o;
    #pragma unroll
    for (int j = 0; j < 8; ++j) o[j] = (short)f2bf(in[i + j]);
    *(short8*)(outp + i) = o;
}

// ---------------- LDS-tiled transpose + cast: Wt[nOff+n][k] = W[k][n] ----------------
__global__ __launch_bounds__(256)
void transpose_cast(const float* __restrict__ W, ushort_t* __restrict__ Wt,
                    int K, int Nsub, int nOff, int ldT)
{
    __shared__ float t[32][33];
    const int k0 = blockIdx.x * 32, n0 = blockIdx.y * 32;
    const int tx = threadIdx.x & 31, ty = threadIdx.x >> 5;   // 32 x 8
    #pragma unroll
    for (int i = 0; i < 4; ++i)
        t[ty + 8*i][tx] = W[(size_t)(k0 + ty + 8*i) * Nsub + (n0 + tx)];
    __syncthreads();
    #pragma unroll
    for (int i = 0; i < 4; ++i)
        Wt[(size_t)(nOff + n0 + ty + 8*i) * ldT + (k0 + tx)] = f2bf(t[tx][ty + 8*i]);
}

// ---- z-batched variant for the three 512-col projection weights ----
__global__ __launch_bounds__(256)
void transpose_cast3(const float* __restrict__ W0, const float* __restrict__ W1,
                     const float* __restrict__ W2, ushort_t* __restrict__ Wt, int ldT)
{
    __shared__ float t[32][33];
    const int z = blockIdx.z;
    const float* W = (z == 0) ? W0 : (z == 1) ? W1 : W2;
    const int nOff = 512 * z;
    const int k0 = blockIdx.x * 32, n0 = blockIdx.y * 32;
    const int tx = threadIdx.x & 31, ty = threadIdx.x >> 5;
    #pragma unroll
    for (int i = 0; i < 4; ++i)
        t[ty + 8*i][tx] = W[(size_t)(k0 + ty + 8*i) * 512 + (n0 + tx)];
    __syncthreads();
    #pragma unroll
    for (int i = 0; i < 4; ++i)
        Wt[(size_t)(nOff + n0 + ty + 8*i) * ldT + (k0 + tx)] = f2bf(t[tx][ty + 8*i]);
}

// ---- consolidated small prep: ctxW transpose (blocks 0-63), zero pad rows
// 1600-1663 (blocks 64-95), concat bias (blocks 96-102) ----
__global__ __launch_bounds__(256)
void prep_small(const float* __restrict__ ctxW,
                const float* __restrict__ qab, const float* __restrict__ kab,
                const float* __restrict__ vab, const float* __restrict__ ctxb,
                ushort_t* __restrict__ WcatT, float* __restrict__ bcat)
{
    __shared__ float t[32][33];
    const int bid = blockIdx.x;
    if (bid < 64) {
        const int k0 = (bid >> 1) * 32, n0 = (bid & 1) * 32;
        const int tx = threadIdx.x & 31, ty = threadIdx.x >> 5;
        #pragma unroll
        for (int i = 0; i < 4; ++i)
            t[ty + 8*i][tx] = ctxW[(size_t)(k0 + ty + 8*i) * 64 + (n0 + tx)];
        __syncthreads();
        #pragma unroll
        for (int i = 0; i < 4; ++i)
            WcatT[(size_t)(1536 + n0 + ty + 8*i) * Ee + (k0 + tx)] = f2bf(t[tx][ty + 8*i]);
    } else if (bid < 96) {
        const int idx = (bid - 64) * 2048 + threadIdx.x * 8;
        short8 z = {0, 0, 0, 0, 0, 0, 0, 0};
        *(short8*)(WcatT + (size_t)1600 * Ee + idx) = z;
    } else {
        const int n = (bid - 96) * 256 + threadIdx.x;
        if (n < NCAT) {
            float v = 0.f;
            if      (n < 512)  v = qab[n];
            else if (n < 1024) v = kab[n - 512];
            else if (n < 1536) v = vab[n - 1024];
            else if (n < 1600) v = ctxb[n - 1536];
            bcat[n] = v;
        }
    }
}

// ---------------- bf16 MFMA GEMM: C = A[M,K] @ Bt[N,K]^T + bias (+res) ----------------
// 128x128 tile, BK=32, 4 waves (2x2), each wave 64x64 = 4x4 fragments of 16x16x32.
// T1: XCD-bijective block swizzle.
template<int RES, int OUTBF>
__global__ __launch_bounds__(256)
void gemm_mfma(const ushort_t* __restrict__ A, const ushort_t* __restrict__ Bt,
               const float* __restrict__ bias, const float* __restrict__ res,
               void* __restrict__ Cout, int M, int N, int K)
{
    __shared__ ushort_t Al[128 * 32];
    __shared__ ushort_t Bl[128 * 32];
    const int tid  = threadIdx.x;
    const int lane = tid & 63;
    const int wave = tid >> 6;       // 0..3
    const int wm = wave >> 1;        // 0..1
    const int wn = wave & 1;         // 0..1

    // XCD-aware bijective swizzle: XCD c gets a contiguous chunk of tiles
    const unsigned nx  = gridDim.x;
    const unsigned bid = blockIdx.y * nx + blockIdx.x;
    const unsigned nwg = nx * gridDim.y;
    const unsigned qc = nwg >> 3, rc = nwg & 7;
    const unsigned xc = bid & 7, of = bid >> 3;
    const unsigned tile = (xc < rc ? xc * (qc + 1) : rc * (qc + 1) + (xc - rc) * qc) + of;
    const int bm = (int)(tile / nx) * 128;
    const int bn = (int)(tile % nx) * 128;

    f32x4 acc[4][4] = {};            // [mi][ni]

    // staging mapping: issue i covers rows i*64 + wave*16 + lane/4, k-quad lane%4
    const int arow0 = wave * 16 + (lane >> 2);
    const int kq = lane & 3;
    const ushort_t* Ag0 = A  + (size_t)(bm + arow0) * K + kq * 8;
    const ushort_t* Ag1 = A  + (size_t)(bm + 64 + arow0) * K + kq * 8;
    const ushort_t* Bg0 = Bt + (size_t)(bn + arow0) * K + kq * 8;
    const ushort_t* Bg1 = Bt + (size_t)(bn + 64 + arow0) * K + kq * 8;
    ushort_t* Alw = Al + wave * 512;   // per-wave 1KB segment (512 elems)
    ushort_t* Blw = Bl + wave * 512;

    const int fr = lane & 15;        // fragment row/col
    const int fg = lane >> 4;        // k-group

    for (int k0 = 0; k0 < K; k0 += 32) {
        GLD16(Ag0 + k0, Alw);
        GLD16(Ag1 + k0, Alw + 2048);
        GLD16(Bg0 + k0, Blw);
        GLD16(Bg1 + k0, Blw + 2048);
        __syncthreads();
        short8 af[4], bfv[4];
        #pragma unroll
        for (int mi = 0; mi < 4; ++mi)
            af[mi] = *(const short8*)&Al[(wm*64 + mi*16 + fr) * 32 + fg * 8];
        #pragma unroll
        for (int ni = 0; ni < 4; ++ni)
            bfv[ni] = *(const short8*)&Bl[(wn*64 + ni*16 + fr) * 32 + fg * 8];
        #pragma unroll
        for (int mi = 0; mi < 4; ++mi)
            #pragma unroll
            for (int ni = 0; ni < 4; ++ni)
                acc[mi][ni] = __builtin_amdgcn_mfma_f32_16x16x32_bf16(
                    af[mi], bfv[ni], acc[mi][ni], 0, 0, 0);
        __syncthreads();
    }

    // epilogue: C/D layout col=lane&15, row=(lane>>4)*4+reg  [HW-verified m89/m91]
    float bv[4];
    #pragma unroll
    for (int ni = 0; ni < 4; ++ni) bv[ni] = bias[bn + wn*64 + ni*16 + fr];
    #pragma unroll
    for (int mi = 0; mi < 4; ++mi) {
        #pragma unroll
        for (int ni = 0; ni < 4; ++ni) {
            const int gn = bn + wn*64 + ni*16 + fr;
            #pragma unroll
            for (int r = 0; r < 4; ++r) {
                const int gm = bm + wm*64 + mi*16 + fg*4 + r;
                float v = acc[mi][ni][r] + bv[ni];
                if (RES) v += res[(size_t)gm * N + gn];
                if (OUTBF) ((ushort_t*)Cout)[(size_t)gm * N + gn] = f2bf(v);
                else       ((float*)Cout)[(size_t)gm * N + gn] = v;
            }
        }
    }
}

// ---------------- fused small-proj + TPA combine + quantum features ----------------
// 256 threads = 4 waves; wave w handles (b,s) = blockIdx.x*4 + w; lane = dim d.
__global__ __launch_bounds__(256)
void combine_quantum(const ushort_t* __restrict__ Cf,
                     const float* __restrict__ qbW, const float* __restrict__ qbb,
                     const float* __restrict__ kbW, const float* __restrict__ kbb,
                     const float* __restrict__ vbW, const float* __restrict__ vbb,
                     const float* __restrict__ qeW, const float* __restrict__ qeb,
                     const float* __restrict__ vqc, const float* __restrict__ ent,
                     float* __restrict__ qf_g, float* __restrict__ kf_g,
                     float* __restrict__ v_g)
{
    const int wid = threadIdx.x >> 6;   // 0..3 wave id
    const int d   = threadIdx.x & 63;   // lane
    const int bs  = blockIdx.x * 4 + wid;
    const int b = bs >> 11;             // S=2048
    const int s = bs & 2047;

    __shared__ float qew_s[HD*NQ];      // [dd*8+i], block-shared
    __shared__ float ctx_l[4][CDd];
    __shared__ float bfq[4][128];       // [r*16+h]
    __shared__ float bfk[4][32];        // [r*4+kvh]
    __shared__ float bfv[4][32];
    __shared__ float rows[4][Hh+KVh][65];

    #pragma unroll
    for (int i = 0; i < 2; ++i)
        qew_s[threadIdx.x + 256*i] = qeW[threadIdx.x + 256*i];

    const ushort_t* Crow = Cf + (size_t)bs * NCAT;
    ctx_l[wid][d] = bf2f(Crow[1536 + d]);
    __syncthreads();

    // small projections: qb (n=d, d+64), kb (lanes 0-31), vb (lanes 32-63)
    {
        float q0 = qbb[d], q1 = qbb[d + 64];
        float kv = (d < 32) ? kbb[d] : vbb[d - 32];
        const float* Wkv = (d < 32) ? (kbW + d) : (vbW + (d - 32));
        #pragma unroll 8
        for (int k = 0; k < CDd; ++k) {
            const float c = ctx_l[wid][k];
            q0 += c * qbW[(size_t)k*128 + d];
            q1 += c * qbW[(size_t)k*128 + d + 64];
            kv += c * Wkv[(size_t)k*32];
        }
        bfq[wid][d] = q0; bfq[wid][d + 64] = q1;
        if (d < 32) bfk[wid][d] = kv; else bfv[wid][d - 32] = kv;
    }

    // TPA A-factors: lane d owns dim d
    float aq[RNK], ak[RNK], av[RNK];
    #pragma unroll
    for (int r = 0; r < RNK; ++r) {
        aq[r] = bf2f(Crow[r*64 + d]);
        ak[r] = bf2f(Crow[512 + r*64 + d]);
        av[r] = bf2f(Crow[1024 + r*64 + d]);
    }
    __syncthreads();

    #pragma unroll
    for (int h = 0; h < Hh; ++h) {
        float acc = 0.f;
        #pragma unroll
        for (int r = 0; r < RNK; ++r) acc += aq[r] * bfq[wid][r*16 + h];
        rows[wid][h][d] = acc;
    }
    #pragma unroll
    for (int kvh = 0; kvh < KVh; ++kvh) {
        float acck = 0.f, accv = 0.f;
        #pragma unroll
        for (int r = 0; r < RNK; ++r) {
            acck += ak[r] * bfk[wid][r*4 + kvh];
            accv += av[r] * bfv[wid][r*4 + kvh];
        }
        rows[wid][Hh + kvh][d] = acck;
        v_g[((size_t)(b*KVh + kvh)*Ss + s)*HD + d] = accv;
    }
    __syncthreads();

    // ---- angle + VQC + features: lane = (row, qubit) task, 3 stripes ----
    const float entv = ent[0];
    const int i   = d & 7;                       // qubit
    const int src = (d & ~7) | ((i + 7) & 7);    // lane of qubit i-1 (mod 8)
    float p00 = vqc[(0*NQ + i)*3 + 0], p01 = vqc[(0*NQ + i)*3 + 1], p02 = vqc[(0*NQ + i)*3 + 2];
    float p10 = vqc[(1*NQ + i)*3 + 0], p11 = vqc[(1*NQ + i)*3 + 1], p12 = vqc[(1*NQ + i)*3 + 2];
    const float qebi = qeb[i];

    #pragma unroll
    for (int stripe = 0; stripe < 3; ++stripe) {
        const int row = stripe * 8 + (d >> 3);
        const bool active = (row < Hh + KVh);
        const int rowc = active ? row : (Hh + KVh - 1);
        float acc = qebi;
        #pragma unroll 16
        for (int dd = 0; dd < HD; ++dd)
            acc += rows[wid][rowc][dd] * qew_s[dd*8 + i];
        float f = tanhf(acc) * 3.14159265358979323846f;
        // layer 0
        float g = cosf(f + p00) * sinf(f + p01) + cosf(f + p02);
        float gp = __shfl(g, src, 64);
        f = g * (1.f + entv * gp);
        // layer 1
        g = cosf(f + p10) * sinf(f + p11) + cosf(f + p12);
        gp = __shfl(g, src, 64);
        f = g * (1.f + entv * gp);
        // features + 8-group norm
        float c = cosf(f), sn = sinf(f);
        float ss = c*c + sn*sn;
        ss += __shfl_xor(ss, 1, 64);
        ss += __shfl_xor(ss, 2, 64);
        ss += __shfl_xor(ss, 4, 64);
        const float inv = 1.f / (sqrtf(ss) + 1e-6f);
        if (active) {
            float* dst = (row < Hh)
                ? qf_g + ((size_t)(b*Hh + row)*Ss + s)*NF
                : kf_g + ((size_t)(b*KVh + (row - Hh))*Ss + s)*NF;
            dst[i]      = c * inv;
            dst[NQ + i] = sn * inv;
        }
    }
}

// ---------------- chunk partial KV state sums, per (b,kvh,chunk) ----------------
// kf reads are wave-uniform -> scalar loads; no LDS.
__global__ __launch_bounds__(64)
void chunk_partial(const float* __restrict__ kf_g, const float* __restrict__ v_g,
                   float* __restrict__ kvpart, float* __restrict__ kfpart)
{
    const int id = blockIdx.x;
    const int c = id & (NC-1);
    const int bk = id / NC;
    const int d = threadIdx.x;
    const int s0 = c * CT;
    const float* kfp = kf_g + ((size_t)bk*Ss + s0)*NF;
    const float* vp  = v_g  + ((size_t)bk*Ss + s0)*HD;
    float st[NF] = {};
    #pragma unroll 2
    for (int t = 0; t < CT; ++t) {
        const float vd = vp[(size_t)t*HD + d];
        #pragma unroll
        for (int f = 0; f < NF; ++f) st[f] += kfp[t*NF + f] * vd;
    }
    float* kvp = kvpart + (size_t)id * (NF*HD);
    #pragma unroll
    for (int f = 0; f < NF; ++f) kvp[f*HD + d] = st[f];
    if (d < NF) {
        float acc = 0.f;
        for (int t = 0; t < CT; ++t) acc += kfp[t*NF + d];
        kfpart[(size_t)id*NF + d] = acc;
    }
}

// ---------------- exclusive prefix over chunks ----------------
__global__ void prefix_scan(float* __restrict__ kvpart, float* __restrict__ kfpart)
{
    const int idx = blockIdx.x * blockDim.x + threadIdx.x;
    const int total = Bb*KVh * (NF*HD + NF);
    if (idx >= total) return;
    const int bk = idx / (NF*HD + NF);
    const int e = idx % (NF*HD + NF);
    if (e < NF*HD) {
        float* p = kvpart + (size_t)bk*NC*(NF*HD) + e;
        float run = 0.f;
        for (int c = 0; c < NC; ++c) {
            const float t = p[(size_t)c*(NF*HD)];
            p[(size_t)c*(NF*HD)] = run;
            run += t;
        }
    } else {
        const int f = e - NF*HD;
        float* p = kfpart + (size_t)bk*NC*NF + f;
        float run = 0.f;
        for (int c = 0; c < NC; ++c) {
            const float t = p[(size_t)c*NF];
            p[(size_t)c*NF] = run;
            run += t;
        }
    }
}

// ---------------- attention scan, per (b,h,chunk); writes bf16 o ----------------
// kf/qf reads are wave-uniform -> scalar loads; no LDS, no barriers.
__global__ __launch_bounds__(64)
void attn_scan(const float* __restrict__ qf_g, const float* __restrict__ kf_g,
               const float* __restrict__ v_g,
               const float* __restrict__ kvpart, const float* __restrict__ kfpart,
               ushort_t* __restrict__ o_bf)
{
    const int id = blockIdx.x;
    const int c = id & (NC-1);
    const int bh = id / NC;
    const int h = bh & (Hh-1);
    const int b = bh / Hh;
    const int kvh = h >> 2;
    const int d = threadIdx.x;
    const int s0 = c * CT;
    const float* kfp = kf_g + ((size_t)(b*KVh + kvh)*Ss + s0)*NF;
    const float* qfp = qf_g + ((size_t)(b*Hh + h)*Ss + s0)*NF;
    float st[NF], kfs[NF];
    const float* kvp  = kvpart + ((size_t)(b*KVh + kvh)*NC + c)*(NF*HD);
    const float* kfsp = kfpart + ((size_t)(b*KVh + kvh)*NC + c)*NF;
    #pragma unroll
    for (int f = 0; f < NF; ++f) { st[f] = kvp[f*HD + d]; kfs[f] = kfsp[f]; }
    const float* vp = v_g + ((size_t)(b*KVh + kvh)*Ss + s0)*HD;
    ushort_t* op = o_bf + ((size_t)(b*Ss + s0))*Ee + h*HD;
    #pragma unroll 2
    for (int t = 0; t < CT; ++t) {
        const float vd = vp[(size_t)t*HD + d];
        float num0 = 0.f, num1 = 0.f, den0 = 0.f, den1 = 0.f;
        #pragma unroll
        for (int f = 0; f < NF; f += 2) {
            const float kv0 = kfp[t*NF + f];
            const float kv1 = kfp[t*NF + f + 1];
            st[f]   += kv0 * vd;   kfs[f]   += kv0;
            st[f+1] += kv1 * vd;   kfs[f+1] += kv1;
            const float qv0 = qfp[t*NF + f];
            const float qv1 = qfp[t*NF + f + 1];
            num0 += qv0 * st[f];   den0 += qv0 * kfs[f];
            num1 += qv1 * st[f+1]; den1 += qv1 * kfs[f+1];
        }
        op[(size_t)t*Ee + d] = f2bf((num0 + num1) / ((den0 + den1) + 1e-6f));
    }
}

// ---------------- residual + LayerNorm: out = LN(x + o_bf16), vectorized ----------------
__global__ __launch_bounds__(256)
void layernorm_res(const float* __restrict__ x, const ushort_t* __restrict__ o_bf,
                   const float* __restrict__ gamma, const float* __restrict__ beta,
                   float* __restrict__ out)
{
    __shared__ float tmp[4];
    const int row = blockIdx.x;
    const int t = threadIdx.x;
    const float* xp = x + (size_t)row * Ee;
    const ushort_t* op = o_bf + (size_t)row * Ee;
    const f32x4 xv = *(const f32x4*)(xp + t*4);
    const u16x4 ov = *(const u16x4*)(op + t*4);
    float v[4];
    float sum = 0.f;
    #pragma unroll
    for (int i = 0; i < 4; ++i) { v[i] = xv[i] + bf2f(ov[i]); sum += v[i]; }
    #pragma unroll
    for (int o = 32; o > 0; o >>= 1) sum += __shfl_down(sum, o, 64);
    if ((t & 63) == 0) tmp[t >> 6] = sum;
    __syncthreads();
    const float mu = (tmp[0] + tmp[1] + tmp[2] + tmp[3]) * (1.f/Ee);
    __syncthreads();
    float vs = 0.f;
    #pragma unroll
    for (int i = 0; i < 4; ++i) { const float dd = v[i] - mu; vs += dd*dd; }
    #pragma unroll
    for (int o = 32; o > 0; o >>= 1) vs += __shfl_down(vs, o, 64);
    if ((t & 63) == 0) tmp[t >> 6] = vs;
    __syncthreads();
    const float var = (tmp[0] + tmp[1] + tmp[2] + tmp[3]) * (1.f/Ee);
    const float inv = rsqrtf(var + 1e-5f);
    const f32x4 gv = *(const f32x4*)(gamma + t*4);
    const f32x4 bv = *(const f32x4*)(beta + t*4);
    f32x4 ovec;
    #pragma unroll
    for (int i = 0; i < 4; ++i) ovec[i] = gv[i] * (v[i] - mu) * inv + bv[i];
    *(f32x4*)(out + (size_t)row * Ee + t*4) = ovec;
}

extern "C" void kernel_launch(void* const* d_in, const int* in_sizes, int n_in,
                              void* d_out, int out_size, void* d_ws, size_t ws_size,
                              hipStream_t stream)
{
    const float* x    = (const float*)d_in[0];
    const float* ctxW = (const float*)d_in[1];
    const float* ctxb = (const float*)d_in[2];
    const float* qaW  = (const float*)d_in[3];
    const float* qab  = (const float*)d_in[4];
    const float* qbW  = (const float*)d_in[5];
    const float* qbb  = (const float*)d_in[6];
    const float* kaW  = (const float*)d_in[7];
    const float* kab  = (const float*)d_in[8];
    const float* kbW  = (const float*)d_in[9];
    const float* kbb  = (const float*)d_in[10];
    const float* vaW  = (const float*)d_in[11];
    const float* vab  = (const float*)d_in[12];
    const float* vbW  = (const float*)d_in[13];
    const float* vbb  = (const float*)d_in[14];
    const float* qeW  = (const float*)d_in[15];
    const float* qeb  = (const float*)d_in[16];
    const float* vqc  = (const float*)d_in[17];
    const float* ent  = (const float*)d_in[18];
    const float* outW = (const float*)d_in[19];
    const float* outb = (const float*)d_in[20];
    const float* gamma= (const float*)d_in[21];
    const float* beta = (const float*)d_in[22];
    float* out = (float*)d_out;

    // workspace layout (bytes, 256-aligned)
    char* p = (char*)d_ws;
    auto alloc = [&](size_t bytes) { char* r = p; p += (bytes + 255) & ~(size_t)255; return (void*)r; };
    ushort_t* xb    = (ushort_t*)alloc((size_t)BS * Ee * 2);          // 16.8 MB
    ushort_t* WcatT = (ushort_t*)alloc((size_t)NCAT * Ee * 2);        //  3.4 MB
    ushort_t* outWt = (ushort_t*)alloc((size_t)Ee * Ee * 2);          //  2.1 MB
    float*    bcat  = (float*)   alloc(NCAT * 4);
    ushort_t* Cf    = (ushort_t*)alloc((size_t)BS * NCAT * 2);        // 27.3 MB
    float*    qf    = (float*)   alloc((size_t)Bb*Hh*Ss*NF * 4);      //  8.4 MB
    float*    kf    = (float*)   alloc((size_t)Bb*KVh*Ss*NF * 4);     //  2.1 MB
    float*    vg    = (float*)   alloc((size_t)Bb*KVh*Ss*HD * 4);     //  8.4 MB
    float*    kvpart= (float*)   alloc((size_t)Bb*KVh*NC*NF*HD * 4);  //  2.1 MB
    float*    kfpart= (float*)   alloc((size_t)Bb*KVh*NC*NF * 4);
    ushort_t* obf2  = (ushort_t*)alloc((size_t)BS * Ee * 2);          // 16.8 MB
    ushort_t* obf   = Cf;   // alias: Cf dead after combine_quantum

    // 0) casts & weight transforms (every call; ws is re-poisoned)
    cast_f32_bf16<<<(BS*(long)Ee/8 + 255)/256, 256, 0, stream>>>(x, xb, (long)BS*Ee);
    transpose_cast3<<<dim3(32, 16, 3), 256, 0, stream>>>(qaW, kaW, vaW, WcatT, Ee);
    prep_small<<<103, 256, 0, stream>>>(ctxW, qab, kab, vab, ctxb, WcatT, bcat);
    transpose_cast<<<dim3(32, 32), 256, 0, stream>>>(outW, outWt, Ee, 1024, 0, Ee);

    // 1) fused projection GEMM: [8192,1024] @ [1024,1664] -> bf16
    gemm_mfma<0,1><<<dim3(NCAT/128, BS/128), 256, 0, stream>>>(
        xb, WcatT, bcat, nullptr, Cf, BS, NCAT, Ee);
    // 2+3) fused small-proj + TPA combine + quantum features (4 (b,s) per block)
    combine_quantum<<<BS/4, 256, 0, stream>>>(Cf, qbW, qbb, kbW, kbb, vbW, vbb,
                                              qeW, qeb, vqc, ent, qf, kf, vg);
    // 4) causal linear attention
    chunk_partial<<<Bb*KVh*NC, 64, 0, stream>>>(kf, vg, kvpart, kfpart);
    prefix_scan<<<(Bb*KVh*(NF*HD + NF) + 255)/256, 256, 0, stream>>>(kvpart, kfpart);
    attn_scan<<<Bb*Hh*NC, 64, 0, stream>>>(qf, kf, vg, kvpart, kfpart, obf);
    // 5) out projection (bf16 out, no res), then fused residual+LayerNorm
    gemm_mfma<0,1><<<dim3(Ee/128, BS/128), 256, 0, stream>>>(
        obf, outWt, outb, nullptr, obf2, BS, Ee, Ee);
    layernorm_res<<<BS, 256, 0, stream>>>(x, obf2, gamma, beta, out);
}

// Round 8
// 303.562 us; speedup vs baseline: 1.0398x; 1.0398x over previous
//
#include <hip/hip_runtime.h>
#include <math.h>

// Problem constants
#define Bb  4
#define Ss  2048
#define Ee  1024
#define Hh  16
#define KVh 4
#define HD  64
#define RNK 8
#define CDd 64
#define NQ  8
#define NLn 2
#define NF  16          // 2*NQ
#define NC  32          // chunks over S
#define CT  (Ss/NC)     // 64 steps per chunk
#define BS  (Bb*Ss)     // 8192 rows
#define NCAT 1664       // 512 qa + 512 ka + 512 va + 64 ctx + 64 pad

typedef unsigned short ushort_t;
typedef __attribute__((ext_vector_type(8))) short short8;
typedef __attribute__((ext_vector_type(4))) float f32x4;
typedef __attribute__((ext_vector_type(4))) unsigned short u16x4;

__device__ __forceinline__ unsigned short f2bf(float f) {
    unsigned int u = __float_as_uint(f);
    unsigned int r = (u + 0x7FFFu + ((u >> 16) & 1u)) >> 16;
    return (unsigned short)r;
}
__device__ __forceinline__ float bf2f(unsigned short h) {
    return __uint_as_float(((unsigned int)h) << 16);
}

#define GLD16(gp, lp) \
    __builtin_amdgcn_global_load_lds((const __attribute__((address_space(1))) void*)(gp), \
                                     (__attribute__((address_space(3))) void*)(lp), 16, 0, 0)

// ---------------- cast f32 -> bf16, 8 elems/thread ----------------
__global__ __launch_bounds__(256)
void cast_f32_bf16(const float* __restrict__ in, ushort_t* __restrict__ outp, long n)
{
    long i = ((long)blockIdx.x * blockDim.x + threadIdx.x) * 8;
    if (i >= n) return;
    short8 o;
    #pragma unroll
    for (int j = 0; j < 8; ++j) o[j] = (short)f2bf(in[i + j]);
    *(short8*)(outp + i) = o;
}

// ---------------- consolidated weight prep (one launch) ----------------
// blocks [0,1536):   qaW/kaW/vaW transpose+cast into WcatT rows 0..1535
// blocks [1536,2560): outW transpose+cast into outWt
// blocks [2560,2663): ctxW transpose (64), zero pad rows (32), bias concat (7)
__global__ __launch_bounds__(256)
void weight_prep(const float* __restrict__ qaW, const float* __restrict__ kaW,
                 const float* __restrict__ vaW, const float* __restrict__ outW,
                 const float* __restrict__ ctxW,
                 const float* __restrict__ qab, const float* __restrict__ kab,
                 const float* __restrict__ vab, const float* __restrict__ ctxb,
                 ushort_t* __restrict__ WcatT, ushort_t* __restrict__ outWt,
                 float* __restrict__ bcat)
{
    __shared__ float t[32][33];
    const int bid = blockIdx.x;
    const int tx = threadIdx.x & 31, ty = threadIdx.x >> 5;   // 32 x 8
    if (bid < 1536) {
        const int z = bid >> 9;              // 0..2
        const int r = bid & 511;
        const int k0 = (r & 31) * 32, n0 = (r >> 5) * 32;
        const float* W = (z == 0) ? qaW : (z == 1) ? kaW : vaW;
        const int nOff = 512 * z;
        #pragma unroll
        for (int i = 0; i < 4; ++i)
            t[ty + 8*i][tx] = W[(size_t)(k0 + ty + 8*i) * 512 + (n0 + tx)];
        __syncthreads();
        #pragma unroll
        for (int i = 0; i < 4; ++i)
            WcatT[(size_t)(nOff + n0 + ty + 8*i) * Ee + (k0 + tx)] = f2bf(t[tx][ty + 8*i]);
    } else if (bid < 2560) {
        const int r = bid - 1536;
        const int k0 = (r & 31) * 32, n0 = (r >> 5) * 32;
        #pragma unroll
        for (int i = 0; i < 4; ++i)
            t[ty + 8*i][tx] = outW[(size_t)(k0 + ty + 8*i) * 1024 + (n0 + tx)];
        __syncthreads();
        #pragma unroll
        for (int i = 0; i < 4; ++i)
            outWt[(size_t)(n0 + ty + 8*i) * Ee + (k0 + tx)] = f2bf(t[tx][ty + 8*i]);
    } else {
        const int pid = bid - 2560;
        if (pid < 64) {
            const int k0 = (pid >> 1) * 32, n0 = (pid & 1) * 32;
            #pragma unroll
            for (int i = 0; i < 4; ++i)
                t[ty + 8*i][tx] = ctxW[(size_t)(k0 + ty + 8*i) * 64 + (n0 + tx)];
            __syncthreads();
            #pragma unroll
            for (int i = 0; i < 4; ++i)
                WcatT[(size_t)(1536 + n0 + ty + 8*i) * Ee + (k0 + tx)] = f2bf(t[tx][ty + 8*i]);
        } else if (pid < 96) {
            const int idx = (pid - 64) * 2048 + threadIdx.x * 8;
            short8 z = {0, 0, 0, 0, 0, 0, 0, 0};
            *(short8*)(WcatT + (size_t)1600 * Ee + idx) = z;
        } else {
            const int n = (pid - 96) * 256 + threadIdx.x;
            if (n < NCAT) {
                float v = 0.f;
                if      (n < 512)  v = qab[n];
                else if (n < 1024) v = kab[n - 512];
                else if (n < 1536) v = vab[n - 1024];
                else if (n < 1600) v = ctxb[n - 1536];
                bcat[n] = v;
            }
        }
    }
}

// ---------------- bf16 MFMA GEMM: C = A[M,K] @ Bt[N,K]^T + bias (+res) ----------------
// 128x128 tile, BK=32, 4 waves (2x2), each wave 64x64 = 4x4 fragments of 16x16x32.
// T1: XCD-bijective block swizzle.
template<int RES, int OUTBF>
__global__ __launch_bounds__(256)
void gemm_mfma(const ushort_t* __restrict__ A, const ushort_t* __restrict__ Bt,
               const float* __restrict__ bias, const float* __restrict__ res,
               void* __restrict__ Cout, int M, int N, int K)
{
    __shared__ ushort_t Al[128 * 32];
    __shared__ ushort_t Bl[128 * 32];
    const int tid  = threadIdx.x;
    const int lane = tid & 63;
    const int wave = tid >> 6;       // 0..3
    const int wm = wave >> 1;        // 0..1
    const int wn = wave & 1;         // 0..1

    // XCD-aware bijective swizzle: XCD c gets a contiguous chunk of tiles
    const unsigned nx  = gridDim.x;
    const unsigned bid = blockIdx.y * nx + blockIdx.x;
    const unsigned nwg = nx * gridDim.y;
    const unsigned qc = nwg >> 3, rc = nwg & 7;
    const unsigned xc = bid & 7, of = bid >> 3;
    const unsigned tile = (xc < rc ? xc * (qc + 1) : rc * (qc + 1) + (xc - rc) * qc) + of;
    const int bm = (int)(tile / nx) * 128;
    const int bn = (int)(tile % nx) * 128;

    f32x4 acc[4][4] = {};            // [mi][ni]

    // staging mapping: issue i covers rows i*64 + wave*16 + lane/4, k-quad lane%4
    const int arow0 = wave * 16 + (lane >> 2);
    const int kq = lane & 3;
    const ushort_t* Ag0 = A  + (size_t)(bm + arow0) * K + kq * 8;
    const ushort_t* Ag1 = A  + (size_t)(bm + 64 + arow0) * K + kq * 8;
    const ushort_t* Bg0 = Bt + (size_t)(bn + arow0) * K + kq * 8;
    const ushort_t* Bg1 = Bt + (size_t)(bn + 64 + arow0) * K + kq * 8;
    ushort_t* Alw = Al + wave * 512;   // per-wave 1KB segment (512 elems)
    ushort_t* Blw = Bl + wave * 512;

    const int fr = lane & 15;        // fragment row/col
    const int fg = lane >> 4;        // k-group

    for (int k0 = 0; k0 < K; k0 += 32) {
        GLD16(Ag0 + k0, Alw);
        GLD16(Ag1 + k0, Alw + 2048);
        GLD16(Bg0 + k0, Blw);
        GLD16(Bg1 + k0, Blw + 2048);
        __syncthreads();
        short8 af[4], bfv[4];
        #pragma unroll
        for (int mi = 0; mi < 4; ++mi)
            af[mi] = *(const short8*)&Al[(wm*64 + mi*16 + fr) * 32 + fg * 8];
        #pragma unroll
        for (int ni = 0; ni < 4; ++ni)
            bfv[ni] = *(const short8*)&Bl[(wn*64 + ni*16 + fr) * 32 + fg * 8];
        #pragma unroll
        for (int mi = 0; mi < 4; ++mi)
            #pragma unroll
            for (int ni = 0; ni < 4; ++ni)
                acc[mi][ni] = __builtin_amdgcn_mfma_f32_16x16x32_bf16(
                    af[mi], bfv[ni], acc[mi][ni], 0, 0, 0);
        __syncthreads();
    }

    // epilogue: C/D layout col=lane&15, row=(lane>>4)*4+reg  [HW-verified m89/m91]
    float bv[4];
    #pragma unroll
    for (int ni = 0; ni < 4; ++ni) bv[ni] = bias[bn + wn*64 + ni*16 + fr];
    #pragma unroll
    for (int mi = 0; mi < 4; ++mi) {
        #pragma unroll
        for (int ni = 0; ni < 4; ++ni) {
            const int gn = bn + wn*64 + ni*16 + fr;
            #pragma unroll
            for (int r = 0; r < 4; ++r) {
                const int gm = bm + wm*64 + mi*16 + fg*4 + r;
                float v = acc[mi][ni][r] + bv[ni];
                if (RES) v += res[(size_t)gm * N + gn];
                if (OUTBF) ((ushort_t*)Cout)[(size_t)gm * N + gn] = f2bf(v);
                else       ((float*)Cout)[(size_t)gm * N + gn] = v;
            }
        }
    }
}

// ---------------- fused small-proj + TPA combine + quantum features ----------------
// 256 threads = 4 waves; wave w handles (b,s) = blockIdx.x*4 + w; lane = dim d.
__global__ __launch_bounds__(256)
void combine_quantum(const ushort_t* __restrict__ Cf,
                     const float* __restrict__ qbW, const float* __restrict__ qbb,
                     const float* __restrict__ kbW, const float* __restrict__ kbb,
                     const float* __restrict__ vbW, const float* __restrict__ vbb,
                     const float* __restrict__ qeW, const float* __restrict__ qeb,
                     const float* __restrict__ vqc, const float* __restrict__ ent,
                     float* __restrict__ qf_g, float* __restrict__ kf_g,
                     float* __restrict__ v_g)
{
    const int wid = threadIdx.x >> 6;   // 0..3 wave id
    const int d   = threadIdx.x & 63;   // lane
    const int bs  = blockIdx.x * 4 + wid;
    const int b = bs >> 11;             // S=2048
    const int s = bs & 2047;

    __shared__ float qew_s[HD*NQ];      // [dd*8+i], block-shared
    __shared__ float ctx_l[4][CDd];
    __shared__ float bfq[4][128];       // [r*16+h]
    __shared__ float bfk[4][32];        // [r*4+kvh]
    __shared__ float bfv[4][32];
    __shared__ float rows[4][Hh+KVh][65];

    #pragma unroll
    for (int i = 0; i < 2; ++i)
        qew_s[threadIdx.x + 256*i] = qeW[threadIdx.x + 256*i];

    const ushort_t* Crow = Cf + (size_t)bs * NCAT;
    ctx_l[wid][d] = bf2f(Crow[1536 + d]);
    __syncthreads();

    // small projections: qb (n=d, d+64), kb (lanes 0-31), vb (lanes 32-63)
    {
        float q0 = qbb[d], q1 = qbb[d + 64];
        float kv = (d < 32) ? kbb[d] : vbb[d - 32];
        const float* Wkv = (d < 32) ? (kbW + d) : (vbW + (d - 32));
        #pragma unroll 8
        for (int k = 0; k < CDd; ++k) {
            const float c = ctx_l[wid][k];
            q0 += c * qbW[(size_t)k*128 + d];
            q1 += c * qbW[(size_t)k*128 + d + 64];
            kv += c * Wkv[(size_t)k*32];
        }
        bfq[wid][d] = q0; bfq[wid][d + 64] = q1;
        if (d < 32) bfk[wid][d] = kv; else bfv[wid][d - 32] = kv;
    }

    // TPA A-factors: lane d owns dim d
    float aq[RNK], ak[RNK], av[RNK];
    #pragma unroll
    for (int r = 0; r < RNK; ++r) {
        aq[r] = bf2f(Crow[r*64 + d]);
        ak[r] = bf2f(Crow[512 + r*64 + d]);
        av[r] = bf2f(Crow[1024 + r*64 + d]);
    }
    __syncthreads();

    #pragma unroll
    for (int h = 0; h < Hh; ++h) {
        float acc = 0.f;
        #pragma unroll
        for (int r = 0; r < RNK; ++r) acc += aq[r] * bfq[wid][r*16 + h];
        rows[wid][h][d] = acc;
    }
    #pragma unroll
    for (int kvh = 0; kvh < KVh; ++kvh) {
        float acck = 0.f, accv = 0.f;
        #pragma unroll
        for (int r = 0; r < RNK; ++r) {
            acck += ak[r] * bfk[wid][r*4 + kvh];
            accv += av[r] * bfv[wid][r*4 + kvh];
        }
        rows[wid][Hh + kvh][d] = acck;
        v_g[((size_t)(b*KVh + kvh)*Ss + s)*HD + d] = accv;
    }
    __syncthreads();

    // ---- angle + VQC + features: lane = (row, qubit) task, 3 stripes ----
    const float entv = ent[0];
    const int i   = d & 7;                       // qubit
    const int src = (d & ~7) | ((i + 7) & 7);    // lane of qubit i-1 (mod 8)
    float p00 = vqc[(0*NQ + i)*3 + 0], p01 = vqc[(0*NQ + i)*3 + 1], p02 = vqc[(0*NQ + i)*3 + 2];
    float p10 = vqc[(1*NQ + i)*3 + 0], p11 = vqc[(1*NQ + i)*3 + 1], p12 = vqc[(1*NQ + i)*3 + 2];
    const float qebi = qeb[i];

    #pragma unroll
    for (int stripe = 0; stripe < 3; ++stripe) {
        const int row = stripe * 8 + (d >> 3);
        const bool active = (row < Hh + KVh);
        const int rowc = active ? row : (Hh + KVh - 1);
        float acc = qebi;
        #pragma unroll 16
        for (int dd = 0; dd < HD; ++dd)
            acc += rows[wid][rowc][dd] * qew_s[dd*8 + i];
        float f = tanhf(acc) * 3.14159265358979323846f;
        // layer 0
        float g = cosf(f + p00) * sinf(f + p01) + cosf(f + p02);
        float gp = __shfl(g, src, 64);
        f = g * (1.f + entv * gp);
        // layer 1
        g = cosf(f + p10) * sinf(f + p11) + cosf(f + p12);
        gp = __shfl(g, src, 64);
        f = g * (1.f + entv * gp);
        // features + 8-group norm
        float c = cosf(f), sn = sinf(f);
        float ss = c*c + sn*sn;
        ss += __shfl_xor(ss, 1, 64);
        ss += __shfl_xor(ss, 2, 64);
        ss += __shfl_xor(ss, 4, 64);
        const float inv = 1.f / (sqrtf(ss) + 1e-6f);
        if (active) {
            float* dst = (row < Hh)
                ? qf_g + ((size_t)(b*Hh + row)*Ss + s)*NF
                : kf_g + ((size_t)(b*KVh + (row - Hh))*Ss + s)*NF;
            dst[i]      = c * inv;
            dst[NQ + i] = sn * inv;
        }
    }
}

// ---------------- chunk partial KV state sums, per (b,kvh,chunk) [R6 LDS form] ----------------
__global__ __launch_bounds__(64)
void chunk_partial(const float* __restrict__ kf_g, const float* __restrict__ v_g,
                   float* __restrict__ kvpart, float* __restrict__ kfpart)
{
    const int id = blockIdx.x;
    const int c = id & (NC-1);
    const int bk = id / NC;
    const int d = threadIdx.x;
    __shared__ float kf_l[CT][NF];
    const int s0 = c * CT;
    const float* kfp = kf_g + ((size_t)bk*Ss + s0)*NF;
    #pragma unroll
    for (int t = 0; t < (CT*NF)/64; ++t)
        ((float*)kf_l)[d + 64*t] = kfp[d + 64*t];
    __syncthreads();
    float st[NF] = {};
    const float* vp = v_g + ((size_t)bk*Ss + s0)*HD;
    for (int t = 0; t < CT; ++t) {
        const float vd = vp[(size_t)t*HD + d];
        #pragma unroll
        for (int f = 0; f < NF; ++f) st[f] += kf_l[t][f] * vd;
    }
    float* kvp = kvpart + (size_t)id * (NF*HD);
    #pragma unroll
    for (int f = 0; f < NF; ++f) kvp[f*HD + d] = st[f];
    if (d < NF) {
        float acc = 0.f;
        for (int t = 0; t < CT; ++t) acc += kf_l[t][d];
        kfpart[(size_t)id*NF + d] = acc;
    }
}

// ---------------- attention scan, per (b,h,chunk); fused chunk-prefix; bf16 o ----------------
// [R6 LDS-staged form + inline exclusive-prefix over kvpart/kfpart chunks < c]
__global__ __launch_bounds__(64)
void attn_scan(const float* __restrict__ qf_g, const float* __restrict__ kf_g,
               const float* __restrict__ v_g,
               const float* __restrict__ kvpart, const float* __restrict__ kfpart,
               ushort_t* __restrict__ o_bf)
{
    const int id = blockIdx.x;
    const int c = id & (NC-1);
    const int bh = id / NC;
    const int h = bh & (Hh-1);
    const int b = bh / Hh;
    const int kvh = h >> 2;
    const int d = threadIdx.x;
    __shared__ float kf_l[CT][NF];
    __shared__ float qf_l[CT][NF];
    const int s0 = c * CT;
    const float* kfp = kf_g + ((size_t)(b*KVh + kvh)*Ss + s0)*NF;
    const float* qfp = qf_g + ((size_t)(b*Hh + h)*Ss + s0)*NF;
    #pragma unroll
    for (int t = 0; t < (CT*NF)/64; ++t) {
        ((float*)kf_l)[d + 64*t] = kfp[d + 64*t];
        ((float*)qf_l)[d + 64*t] = qfp[d + 64*t];
    }
    // inline exclusive prefix over chunks [0, c)
    float st[NF] = {};
    float kfs[NF] = {};
    const int bk = b*KVh + kvh;
    for (int cc = 0; cc < c; ++cc) {
        const float* kvp = kvpart + ((size_t)bk*NC + cc)*(NF*HD);
        const float* kfq = kfpart + ((size_t)bk*NC + cc)*NF;
        #pragma unroll
        for (int f = 0; f < NF; ++f) {
            st[f]  += kvp[f*HD + d];
            kfs[f] += kfq[f];
        }
    }
    __syncthreads();
    const float* vp = v_g + ((size_t)(b*KVh + kvh)*Ss + s0)*HD;
    ushort_t* op = o_bf + ((size_t)(b*Ss + s0))*Ee + h*HD;
    for (int t = 0; t < CT; ++t) {
        const float vd = vp[(size_t)t*HD + d];
        float num0 = 0.f, num1 = 0.f, den0 = 0.f, den1 = 0.f;
        #pragma unroll
        for (int f = 0; f < NF; f += 2) {
            const float kv0 = kf_l[t][f];
            const float kv1 = kf_l[t][f+1];
            st[f]   += kv0 * vd;   kfs[f]   += kv0;
            st[f+1] += kv1 * vd;   kfs[f+1] += kv1;
            const float qv0 = qf_l[t][f];
            const float qv1 = qf_l[t][f+1];
            num0 += qv0 * st[f];   den0 += qv0 * kfs[f];
            num1 += qv1 * st[f+1]; den1 += qv1 * kfs[f+1];
        }
        op[(size_t)t*Ee + d] = f2bf((num0 + num1) / ((den0 + den1) + 1e-6f));
    }
}

// ---------------- residual + LayerNorm: out = LN(x + o_bf16), vectorized ----------------
__global__ __launch_bounds__(256)
void layernorm_res(const float* __restrict__ x, const ushort_t* __restrict__ o_bf,
                   const float* __restrict__ gamma, const float* __restrict__ beta,
                   float* __restrict__ out)
{
    __shared__ float tmp[4];
    const int row = blockIdx.x;
    const int t = threadIdx.x;
    const float* xp = x + (size_t)row * Ee;
    const ushort_t* op = o_bf + (size_t)row * Ee;
    const f32x4 xv = *(const f32x4*)(xp + t*4);
    const u16x4 ov = *(const u16x4*)(op + t*4);
    float v[4];
    float sum = 0.f;
    #pragma unroll
    for (int i = 0; i < 4; ++i) { v[i] = xv[i] + bf2f(ov[i]); sum += v[i]; }
    #pragma unroll
    for (int o = 32; o > 0; o >>= 1) sum += __shfl_down(sum, o, 64);
    if ((t & 63) == 0) tmp[t >> 6] = sum;
    __syncthreads();
    const float mu = (tmp[0] + tmp[1] + tmp[2] + tmp[3]) * (1.f/Ee);
    __syncthreads();
    float vs = 0.f;
    #pragma unroll
    for (int i = 0; i < 4; ++i) { const float dd = v[i] - mu; vs += dd*dd; }
    #pragma unroll
    for (int o = 32; o > 0; o >>= 1) vs += __shfl_down(vs, o, 64);
    if ((t & 63) == 0) tmp[t >> 6] = vs;
    __syncthreads();
    const float var = (tmp[0] + tmp[1] + tmp[2] + tmp[3]) * (1.f/Ee);
    const float inv = rsqrtf(var + 1e-5f);
    const f32x4 gv = *(const f32x4*)(gamma + t*4);
    const f32x4 bv = *(const f32x4*)(beta + t*4);
    f32x4 ovec;
    #pragma unroll
    for (int i = 0; i < 4; ++i) ovec[i] = gv[i] * (v[i] - mu) * inv + bv[i];
    *(f32x4*)(out + (size_t)row * Ee + t*4) = ovec;
}

extern "C" void kernel_launch(void* const* d_in, const int* in_sizes, int n_in,
                              void* d_out, int out_size, void* d_ws, size_t ws_size,
                              hipStream_t stream)
{
    const float* x    = (const float*)d_in[0];
    const float* ctxW = (const float*)d_in[1];
    const float* ctxb = (const float*)d_in[2];
    const float* qaW  = (const float*)d_in[3];
    const float* qab  = (const float*)d_in[4];
    const float* qbW  = (const float*)d_in[5];
    const float* qbb  = (const float*)d_in[6];
    const float* kaW  = (const float*)d_in[7];
    const float* kab  = (const float*)d_in[8];
    const float* kbW  = (const float*)d_in[9];
    const float* kbb  = (const float*)d_in[10];
    const float* vaW  = (const float*)d_in[11];
    const float* vab  = (const float*)d_in[12];
    const float* vbW  = (const float*)d_in[13];
    const float* vbb  = (const float*)d_in[14];
    const float* qeW  = (const float*)d_in[15];
    const float* qeb  = (const float*)d_in[16];
    const float* vqc  = (const float*)d_in[17];
    const float* ent  = (const float*)d_in[18];
    const float* outW = (const float*)d_in[19];
    const float* outb = (const float*)d_in[20];
    const float* gamma= (const float*)d_in[21];
    const float* beta = (const float*)d_in[22];
    float* out = (float*)d_out;

    // workspace layout (bytes, 256-aligned); ~71 MB
    char* p = (char*)d_ws;
    auto alloc = [&](size_t bytes) { char* r = p; p += (bytes + 255) & ~(size_t)255; return (void*)r; };
    ushort_t* xb    = (ushort_t*)alloc((size_t)BS * Ee * 2);          // 16.8 MB
    ushort_t* WcatT = (ushort_t*)alloc((size_t)NCAT * Ee * 2);        //  3.4 MB
    ushort_t* outWt = (ushort_t*)alloc((size_t)Ee * Ee * 2);          //  2.1 MB
    float*    bcat  = (float*)   alloc(NCAT * 4);
    ushort_t* Cf    = (ushort_t*)alloc((size_t)BS * NCAT * 2);        // 27.3 MB
    float*    qf    = (float*)   alloc((size_t)Bb*Hh*Ss*NF * 4);      //  8.4 MB
    float*    kf    = (float*)   alloc((size_t)Bb*KVh*Ss*NF * 4);     //  2.1 MB
    float*    vg    = (float*)   alloc((size_t)Bb*KVh*Ss*HD * 4);     //  8.4 MB
    float*    kvpart= (float*)   alloc((size_t)Bb*KVh*NC*NF*HD * 4);  //  2.1 MB
    float*    kfpart= (float*)   alloc((size_t)Bb*KVh*NC*NF * 4);
    ushort_t* obf   = Cf;                 // alias: Cf dead after combine_quantum
    ushort_t* obf2  = (ushort_t*)qf;      // alias: qf/kf/vg dead after attn_scan (18.9 >= 16.8 MB)

    // 0) input cast + consolidated weight prep
    cast_f32_bf16<<<(BS*(long)Ee/8 + 255)/256, 256, 0, stream>>>(x, xb, (long)BS*Ee);
    weight_prep<<<2663, 256, 0, stream>>>(qaW, kaW, vaW, outW, ctxW,
                                          qab, kab, vab, ctxb, WcatT, outWt, bcat);

    // 1) fused projection GEMM: [8192,1024] @ [1024,1664] -> bf16
    gemm_mfma<0,1><<<dim3(NCAT/128, BS/128), 256, 0, stream>>>(
        xb, WcatT, bcat, nullptr, Cf, BS, NCAT, Ee);
    // 2+3) fused small-proj + TPA combine + quantum features (4 (b,s) per block)
    combine_quantum<<<BS/4, 256, 0, stream>>>(Cf, qbW, qbb, kbW, kbb, vbW, vbb,
                                              qeW, qeb, vqc, ent, qf, kf, vg);
    // 4) causal linear attention: partials -> scan (prefix fused into scan)
    chunk_partial<<<Bb*KVh*NC, 64, 0, stream>>>(kf, vg, kvpart, kfpart);
    attn_scan<<<Bb*Hh*NC, 64, 0, stream>>>(qf, kf, vg, kvpart, kfpart, obf);
    // 5) out projection (bf16 out), then fused residual+LayerNorm
    gemm_mfma<0,1><<<dim3(Ee/128, BS/128), 256, 0, stream>>>(
        obf, outWt, outb, nullptr, obf2, BS, Ee, Ee);
    layernorm_res<<<BS, 256, 0, stream>>>(x, obf2, gamma, beta, out);
}

// Round 9
// 289.029 us; speedup vs baseline: 1.0921x; 1.0503x over previous
//
#include <hip/hip_runtime.h>
#include <math.h>

// Problem constants
#define Bb  4
#define Ss  2048
#define Ee  1024
#define Hh  16
#define KVh 4
#define HD  64
#define RNK 8
#define CDd 64
#define NQ  8
#define NLn 2
#define NF  16          // 2*NQ
#define NC  64          // chunks over S (R9: 32 -> 64, halves serial scan)
#define CT  (Ss/NC)     // 32 steps per chunk
#define BS  (Bb*Ss)     // 8192 rows
#define NCAT 1664       // 512 qa + 512 ka + 512 va + 64 ctx + 64 pad

typedef unsigned short ushort_t;
typedef __attribute__((ext_vector_type(8))) short short8;
typedef __attribute__((ext_vector_type(4))) float f32x4;
typedef __attribute__((ext_vector_type(4))) unsigned short u16x4;

__device__ __forceinline__ unsigned short f2bf(float f) {
    unsigned int u = __float_as_uint(f);
    unsigned int r = (u + 0x7FFFu + ((u >> 16) & 1u)) >> 16;
    return (unsigned short)r;
}
__device__ __forceinline__ float bf2f(unsigned short h) {
    return __uint_as_float(((unsigned int)h) << 16);
}

#define GLD16(gp, lp) \
    __builtin_amdgcn_global_load_lds((const __attribute__((address_space(1))) void*)(gp), \
                                     (__attribute__((address_space(3))) void*)(lp), 16, 0, 0)

// ---------------- consolidated prep: x-cast + all weight transforms (one launch) ----
// blocks [0,4096):      cast x f32->bf16 (2048 elems/block)
// blocks [4096,5632):   qaW/kaW/vaW transpose+cast into WcatT rows 0..1535
// blocks [5632,6656):   outW transpose+cast into outWt
// blocks [6656,6759):   ctxW transpose (64), zero pad rows (32), bias concat (7)
__global__ __launch_bounds__(256)
void prep_all(const float* __restrict__ x, ushort_t* __restrict__ xb,
              const float* __restrict__ qaW, const float* __restrict__ kaW,
              const float* __restrict__ vaW, const float* __restrict__ outW,
              const float* __restrict__ ctxW,
              const float* __restrict__ qab, const float* __restrict__ kab,
              const float* __restrict__ vab, const float* __restrict__ ctxb,
              ushort_t* __restrict__ WcatT, ushort_t* __restrict__ outWt,
              float* __restrict__ bcat)
{
    __shared__ float t[32][33];
    const int bid = blockIdx.x;
    const int tx = threadIdx.x & 31, ty = threadIdx.x >> 5;   // 32 x 8
    if (bid < 4096) {
        const long i = (long)bid * 2048 + threadIdx.x * 8;
        short8 o;
        #pragma unroll
        for (int j = 0; j < 8; ++j) o[j] = (short)f2bf(x[i + j]);
        *(short8*)(xb + i) = o;
    } else if (bid < 5632) {
        const int r0 = bid - 4096;
        const int z = r0 >> 9;               // 0..2
        const int r = r0 & 511;
        const int k0 = (r & 31) * 32, n0 = (r >> 5) * 32;
        const float* W = (z == 0) ? qaW : (z == 1) ? kaW : vaW;
        const int nOff = 512 * z;
        #pragma unroll
        for (int i = 0; i < 4; ++i)
            t[ty + 8*i][tx] = W[(size_t)(k0 + ty + 8*i) * 512 + (n0 + tx)];
        __syncthreads();
        #pragma unroll
        for (int i = 0; i < 4; ++i)
            WcatT[(size_t)(nOff + n0 + ty + 8*i) * Ee + (k0 + tx)] = f2bf(t[tx][ty + 8*i]);
    } else if (bid < 6656) {
        const int r = bid - 5632;
        const int k0 = (r & 31) * 32, n0 = (r >> 5) * 32;
        #pragma unroll
        for (int i = 0; i < 4; ++i)
            t[ty + 8*i][tx] = outW[(size_t)(k0 + ty + 8*i) * 1024 + (n0 + tx)];
        __syncthreads();
        #pragma unroll
        for (int i = 0; i < 4; ++i)
            outWt[(size_t)(n0 + ty + 8*i) * Ee + (k0 + tx)] = f2bf(t[tx][ty + 8*i]);
    } else {
        const int pid = bid - 6656;
        if (pid < 64) {
            const int k0 = (pid >> 1) * 32, n0 = (pid & 1) * 32;
            #pragma unroll
            for (int i = 0; i < 4; ++i)
                t[ty + 8*i][tx] = ctxW[(size_t)(k0 + ty + 8*i) * 64 + (n0 + tx)];
            __syncthreads();
            #pragma unroll
            for (int i = 0; i < 4; ++i)
                WcatT[(size_t)(1536 + n0 + ty + 8*i) * Ee + (k0 + tx)] = f2bf(t[tx][ty + 8*i]);
        } else if (pid < 96) {
            const int idx = (pid - 64) * 2048 + threadIdx.x * 8;
            short8 z = {0, 0, 0, 0, 0, 0, 0, 0};
            *(short8*)(WcatT + (size_t)1600 * Ee + idx) = z;
        } else {
            const int n = (pid - 96) * 256 + threadIdx.x;
            if (n < NCAT) {
                float v = 0.f;
                if      (n < 512)  v = qab[n];
                else if (n < 1024) v = kab[n - 512];
                else if (n < 1536) v = vab[n - 1024];
                else if (n < 1600) v = ctxb[n - 1536];
                bcat[n] = v;
            }
        }
    }
}

// ---------------- bf16 MFMA GEMM: C = A[M,K] @ Bt[N,K]^T + bias (+res) ----------------
// 128x128 tile, BK=32, 4 waves (2x2), each wave 64x64 = 4x4 fragments of 16x16x32.
// T1: XCD-bijective block swizzle.  [UNCHANGED - verified]
template<int RES, int OUTBF>
__global__ __launch_bounds__(256)
void gemm_mfma(const ushort_t* __restrict__ A, const ushort_t* __restrict__ Bt,
               const float* __restrict__ bias, const float* __restrict__ res,
               void* __restrict__ Cout, int M, int N, int K)
{
    __shared__ ushort_t Al[128 * 32];
    __shared__ ushort_t Bl[128 * 32];
    const int tid  = threadIdx.x;
    const int lane = tid & 63;
    const int wave = tid >> 6;       // 0..3
    const int wm = wave >> 1;        // 0..1
    const int wn = wave & 1;         // 0..1

    // XCD-aware bijective swizzle: XCD c gets a contiguous chunk of tiles
    const unsigned nx  = gridDim.x;
    const unsigned bid = blockIdx.y * nx + blockIdx.x;
    const unsigned nwg = nx * gridDim.y;
    const unsigned qc = nwg >> 3, rc = nwg & 7;
    const unsigned xc = bid & 7, of = bid >> 3;
    const unsigned tile = (xc < rc ? xc * (qc + 1) : rc * (qc + 1) + (xc - rc) * qc) + of;
    const int bm = (int)(tile / nx) * 128;
    const int bn = (int)(tile % nx) * 128;

    f32x4 acc[4][4] = {};            // [mi][ni]

    const int arow0 = wave * 16 + (lane >> 2);
    const int kq = lane & 3;
    const ushort_t* Ag0 = A  + (size_t)(bm + arow0) * K + kq * 8;
    const ushort_t* Ag1 = A  + (size_t)(bm + 64 + arow0) * K + kq * 8;
    const ushort_t* Bg0 = Bt + (size_t)(bn + arow0) * K + kq * 8;
    const ushort_t* Bg1 = Bt + (size_t)(bn + 64 + arow0) * K + kq * 8;
    ushort_t* Alw = Al + wave * 512;
    ushort_t* Blw = Bl + wave * 512;

    const int fr = lane & 15;
    const int fg = lane >> 4;

    for (int k0 = 0; k0 < K; k0 += 32) {
        GLD16(Ag0 + k0, Alw);
        GLD16(Ag1 + k0, Alw + 2048);
        GLD16(Bg0 + k0, Blw);
        GLD16(Bg1 + k0, Blw + 2048);
        __syncthreads();
        short8 af[4], bfv[4];
        #pragma unroll
        for (int mi = 0; mi < 4; ++mi)
            af[mi] = *(const short8*)&Al[(wm*64 + mi*16 + fr) * 32 + fg * 8];
        #pragma unroll
        for (int ni = 0; ni < 4; ++ni)
            bfv[ni] = *(const short8*)&Bl[(wn*64 + ni*16 + fr) * 32 + fg * 8];
        #pragma unroll
        for (int mi = 0; mi < 4; ++mi)
            #pragma unroll
            for (int ni = 0; ni < 4; ++ni)
                acc[mi][ni] = __builtin_amdgcn_mfma_f32_16x16x32_bf16(
                    af[mi], bfv[ni], acc[mi][ni], 0, 0, 0);
        __syncthreads();
    }

    // epilogue: C/D layout col=lane&15, row=(lane>>4)*4+reg  [HW-verified m89/m91]
    float bv[4];
    #pragma unroll
    for (int ni = 0; ni < 4; ++ni) bv[ni] = bias[bn + wn*64 + ni*16 + fr];
    #pragma unroll
    for (int mi = 0; mi < 4; ++mi) {
        #pragma unroll
        for (int ni = 0; ni < 4; ++ni) {
            const int gn = bn + wn*64 + ni*16 + fr;
            #pragma unroll
            for (int r = 0; r < 4; ++r) {
                const int gm = bm + wm*64 + mi*16 + fg*4 + r;
                float v = acc[mi][ni][r] + bv[ni];
                if (RES) v += res[(size_t)gm * N + gn];
                if (OUTBF) ((ushort_t*)Cout)[(size_t)gm * N + gn] = f2bf(v);
                else       ((float*)Cout)[(size_t)gm * N + gn] = v;
            }
        }
    }
}

// ---------------- fused small-proj + TPA combine + quantum features ----------------
// 256 threads = 4 waves; wave w handles (b,s) = blockIdx.x*4 + w; lane = dim d.
// small-proj is cooperative: thread t owns weight column n, FMAs vs all 4 s
// (weights loaded ONCE per block instead of once per wave: L2 traffic /4).
__global__ __launch_bounds__(256)
void combine_quantum(const ushort_t* __restrict__ Cf,
                     const float* __restrict__ qbW, const float* __restrict__ qbb,
                     const float* __restrict__ kbW, const float* __restrict__ kbb,
                     const float* __restrict__ vbW, const float* __restrict__ vbb,
                     const float* __restrict__ qeW, const float* __restrict__ qeb,
                     const float* __restrict__ vqc, const float* __restrict__ ent,
                     float* __restrict__ qf_g, float* __restrict__ kf_g,
                     float* __restrict__ v_g)
{
    const int wid = threadIdx.x >> 6;   // 0..3 wave id
    const int d   = threadIdx.x & 63;   // lane
    const int bs  = blockIdx.x * 4 + wid;
    const int b = bs >> 11;             // S=2048
    const int s = bs & 2047;

    __shared__ float qew_s[HD*NQ];      // [dd*8+i], block-shared
    __shared__ float ctx_l[4][CDd];
    __shared__ float bfq[4][128];       // [r*16+h]
    __shared__ float bfk[4][32];        // [r*4+kvh]
    __shared__ float bfv[4][32];
    __shared__ float rows[4][Hh+KVh][65];

    #pragma unroll
    for (int i = 0; i < 2; ++i)
        qew_s[threadIdx.x + 256*i] = qeW[threadIdx.x + 256*i];

    const ushort_t* Crow = Cf + (size_t)bs * NCAT;
    ctx_l[wid][d] = bf2f(Crow[1536 + d]);
    __syncthreads();

    // cooperative small projections: thread t owns output column n for all 4 s
    {
        const int t = threadIdx.x;
        if (t < 192) {
            const float* Wc; float bb; int ldw;
            if (t < 128)      { Wc = qbW + t;         bb = qbb[t];       ldw = 128; }
            else if (t < 160) { Wc = kbW + (t - 128); bb = kbb[t - 128]; ldw = 32;  }
            else              { Wc = vbW + (t - 160); bb = vbb[t - 160]; ldw = 32;  }
            float a0 = bb, a1 = bb, a2 = bb, a3 = bb;
            #pragma unroll 8
            for (int k = 0; k < CDd; ++k) {
                const float w = Wc[(size_t)k * ldw];
                a0 += ctx_l[0][k] * w;
                a1 += ctx_l[1][k] * w;
                a2 += ctx_l[2][k] * w;
                a3 += ctx_l[3][k] * w;
            }
            if (t < 128) {
                bfq[0][t] = a0; bfq[1][t] = a1; bfq[2][t] = a2; bfq[3][t] = a3;
            } else if (t < 160) {
                const int n = t - 128;
                bfk[0][n] = a0; bfk[1][n] = a1; bfk[2][n] = a2; bfk[3][n] = a3;
            } else {
                const int n = t - 160;
                bfv[0][n] = a0; bfv[1][n] = a1; bfv[2][n] = a2; bfv[3][n] = a3;
            }
        }
    }

    // TPA A-factors: lane d owns dim d
    float aq[RNK], ak[RNK], av[RNK];
    #pragma unroll
    for (int r = 0; r < RNK; ++r) {
        aq[r] = bf2f(Crow[r*64 + d]);
        ak[r] = bf2f(Crow[512 + r*64 + d]);
        av[r] = bf2f(Crow[1024 + r*64 + d]);
    }
    __syncthreads();

    #pragma unroll
    for (int h = 0; h < Hh; ++h) {
        float acc = 0.f;
        #pragma unroll
        for (int r = 0; r < RNK; ++r) acc += aq[r] * bfq[wid][r*16 + h];
        rows[wid][h][d] = acc;
    }
    #pragma unroll
    for (int kvh = 0; kvh < KVh; ++kvh) {
        float acck = 0.f, accv = 0.f;
        #pragma unroll
        for (int r = 0; r < RNK; ++r) {
            acck += ak[r] * bfk[wid][r*4 + kvh];
            accv += av[r] * bfv[wid][r*4 + kvh];
        }
        rows[wid][Hh + kvh][d] = acck;
        v_g[((size_t)(b*KVh + kvh)*Ss + s)*HD + d] = accv;
    }
    __syncthreads();

    // ---- angle + VQC + features: lane = (row, qubit) task, 3 stripes ----
    const float entv = ent[0];
    const int i   = d & 7;                       // qubit
    const int src = (d & ~7) | ((i + 7) & 7);    // lane of qubit i-1 (mod 8)
    float p00 = vqc[(0*NQ + i)*3 + 0], p01 = vqc[(0*NQ + i)*3 + 1], p02 = vqc[(0*NQ + i)*3 + 2];
    float p10 = vqc[(1*NQ + i)*3 + 0], p11 = vqc[(1*NQ + i)*3 + 1], p12 = vqc[(1*NQ + i)*3 + 2];
    const float qebi = qeb[i];

    #pragma unroll
    for (int stripe = 0; stripe < 3; ++stripe) {
        const int row = stripe * 8 + (d >> 3);
        const bool active = (row < Hh + KVh);
        const int rowc = active ? row : (Hh + KVh - 1);
        float acc = qebi;
        #pragma unroll 16
        for (int dd = 0; dd < HD; ++dd)
            acc += rows[wid][rowc][dd] * qew_s[dd*8 + i];
        float f = tanhf(acc) * 3.14159265358979323846f;
        // layer 0
        float g = cosf(f + p00) * sinf(f + p01) + cosf(f + p02);
        float gp = __shfl(g, src, 64);
        f = g * (1.f + entv * gp);
        // layer 1
        g = cosf(f + p10) * sinf(f + p11) + cosf(f + p12);
        gp = __shfl(g, src, 64);
        f = g * (1.f + entv * gp);
        // features + 8-group norm
        float c = cosf(f), sn = sinf(f);
        float ss = c*c + sn*sn;
        ss += __shfl_xor(ss, 1, 64);
        ss += __shfl_xor(ss, 2, 64);
        ss += __shfl_xor(ss, 4, 64);
        const float inv = 1.f / (sqrtf(ss) + 1e-6f);
        if (active) {
            float* dst = (row < Hh)
                ? qf_g + ((size_t)(b*Hh + row)*Ss + s)*NF
                : kf_g + ((size_t)(b*KVh + (row - Hh))*Ss + s)*NF;
            dst[i]      = c * inv;
            dst[NQ + i] = sn * inv;
        }
    }
}

// ---------------- chunk partial KV state sums, per (b,kvh,chunk) ----------------
__global__ __launch_bounds__(64)
void chunk_partial(const float* __restrict__ kf_g, const float* __restrict__ v_g,
                   float* __restrict__ kvpart, float* __restrict__ kfpart)
{
    const int id = blockIdx.x;
    const int c = id & (NC-1);
    const int bk = id / NC;
    const int d = threadIdx.x;
    __shared__ float kf_l[CT][NF];
    const int s0 = c * CT;
    const float* kfp = kf_g + ((size_t)bk*Ss + s0)*NF;
    #pragma unroll
    for (int t = 0; t < (CT*NF)/64; ++t)
        ((float*)kf_l)[d + 64*t] = kfp[d + 64*t];
    __syncthreads();
    float st[NF] = {};
    const float* vp = v_g + ((size_t)bk*Ss + s0)*HD;
    for (int t = 0; t < CT; ++t) {
        const float vd = vp[(size_t)t*HD + d];
        #pragma unroll
        for (int f = 0; f < NF; ++f) st[f] += kf_l[t][f] * vd;
    }
    float* kvp = kvpart + (size_t)id * (NF*HD);
    #pragma unroll
    for (int f = 0; f < NF; ++f) kvp[f*HD + d] = st[f];
    if (d < NF) {
        float acc = 0.f;
        for (int t = 0; t < CT; ++t) acc += kf_l[t][d];
        kfpart[(size_t)id*NF + d] = acc;
    }
}

// ---------------- exclusive prefix over chunks (in-place) ----------------
__global__ void prefix_scan(float* __restrict__ kvpart, float* __restrict__ kfpart)
{
    const int idx = blockIdx.x * blockDim.x + threadIdx.x;
    const int total = Bb*KVh * (NF*HD + NF);
    if (idx >= total) return;
    const int bk = idx / (NF*HD + NF);
    const int e = idx % (NF*HD + NF);
    if (e < NF*HD) {
        float* p = kvpart + (size_t)bk*NC*(NF*HD) + e;
        float run = 0.f;
        for (int c = 0; c < NC; ++c) {
            const float t = p[(size_t)c*(NF*HD)];
            p[(size_t)c*(NF*HD)] = run;
            run += t;
        }
    } else {
        const int f = e - NF*HD;
        float* p = kfpart + (size_t)bk*NC*NF + f;
        float run = 0.f;
        for (int c = 0; c < NC; ++c) {
            const float t = p[(size_t)c*NF];
            p[(size_t)c*NF] = run;
            run += t;
        }
    }
}

// ---------------- attention scan, per (b,h,chunk); writes bf16 o ----------------
__global__ __launch_bounds__(64)
void attn_scan(const float* __restrict__ qf_g, const float* __restrict__ kf_g,
               const float* __restrict__ v_g,
               const float* __restrict__ kvpart, const float* __restrict__ kfpart,
               ushort_t* __restrict__ o_bf)
{
    const int id = blockIdx.x;
    const int c = id & (NC-1);
    const int bh = id / NC;
    const int h = bh & (Hh-1);
    const int b = bh / Hh;
    const int kvh = h >> 2;
    const int d = threadIdx.x;
    __shared__ float kf_l[CT][NF];
    __shared__ float qf_l[CT][NF];
    const int s0 = c * CT;
    const float* kfp = kf_g + ((size_t)(b*KVh + kvh)*Ss + s0)*NF;
    const float* qfp = qf_g + ((size_t)(b*Hh + h)*Ss + s0)*NF;
    #pragma unroll
    for (int t = 0; t < (CT*NF)/64; ++t) {
        ((float*)kf_l)[d + 64*t] = kfp[d + 64*t];
        ((float*)qf_l)[d + 64*t] = qfp[d + 64*t];
    }
    float st[NF], kfs[NF];
    const float* kvp  = kvpart + ((size_t)(b*KVh + kvh)*NC + c)*(NF*HD);
    const float* kfsp = kfpart + ((size_t)(b*KVh + kvh)*NC + c)*NF;
    #pragma unroll
    for (int f = 0; f < NF; ++f) { st[f] = kvp[f*HD + d]; kfs[f] = kfsp[f]; }
    __syncthreads();
    const float* vp = v_g + ((size_t)(b*KVh + kvh)*Ss + s0)*HD;
    ushort_t* op = o_bf + ((size_t)(b*Ss + s0))*Ee + h*HD;
    for (int t = 0; t < CT; ++t) {
        const float vd = vp[(size_t)t*HD + d];
        float num0 = 0.f, num1 = 0.f, den0 = 0.f, den1 = 0.f;
        #pragma unroll
        for (int f = 0; f < NF; f += 2) {
            const float kv0 = kf_l[t][f];
            const float kv1 = kf_l[t][f+1];
            st[f]   += kv0 * vd;   kfs[f]   += kv0;
            st[f+1] += kv1 * vd;   kfs[f+1] += kv1;
            const float qv0 = qf_l[t][f];
            const float qv1 = qf_l[t][f+1];
            num0 += qv0 * st[f];   den0 += qv0 * kfs[f];
            num1 += qv1 * st[f+1]; den1 += qv1 * kfs[f+1];
        }
        op[(size_t)t*Ee + d] = f2bf((num0 + num1) / ((den0 + den1) + 1e-6f));
    }
}

// ---------------- residual + LayerNorm: out = LN(x + o_bf16), vectorized ----------------
__global__ __launch_bounds__(256)
void layernorm_res(const float* __restrict__ x, const ushort_t* __restrict__ o_bf,
                   const float* __restrict__ gamma, const float* __restrict__ beta,
                   float* __restrict__ out)
{
    __shared__ float tmp[4];
    const int row = blockIdx.x;
    const int t = threadIdx.x;
    const float* xp = x + (size_t)row * Ee;
    const ushort_t* op = o_bf + (size_t)row * Ee;
    const f32x4 xv = *(const f32x4*)(xp + t*4);
    const u16x4 ov = *(const u16x4*)(op + t*4);
    float v[4];
    float sum = 0.f;
    #pragma unroll
    for (int i = 0; i < 4; ++i) { v[i] = xv[i] + bf2f(ov[i]); sum += v[i]; }
    #pragma unroll
    for (int o = 32; o > 0; o >>= 1) sum += __shfl_down(sum, o, 64);
    if ((t & 63) == 0) tmp[t >> 6] = sum;
    __syncthreads();
    const float mu = (tmp[0] + tmp[1] + tmp[2] + tmp[3]) * (1.f/Ee);
    __syncthreads();
    float vs = 0.f;
    #pragma unroll
    for (int i = 0; i < 4; ++i) { const float dd = v[i] - mu; vs += dd*dd; }
    #pragma unroll
    for (int o = 32; o > 0; o >>= 1) vs += __shfl_down(vs, o, 64);
    if ((t & 63) == 0) tmp[t >> 6] = vs;
    __syncthreads();
    const float var = (tmp[0] + tmp[1] + tmp[2] + tmp[3]) * (1.f/Ee);
    const float inv = rsqrtf(var + 1e-5f);
    const f32x4 gv = *(const f32x4*)(gamma + t*4);
    const f32x4 bv = *(const f32x4*)(beta + t*4);
    f32x4 ovec;
    #pragma unroll
    for (int i = 0; i < 4; ++i) ovec[i] = gv[i] * (v[i] - mu) * inv + bv[i];
    *(f32x4*)(out + (size_t)row * Ee + t*4) = ovec;
}

extern "C" void kernel_launch(void* const* d_in, const int* in_sizes, int n_in,
                              void* d_out, int out_size, void* d_ws, size_t ws_size,
                              hipStream_t stream)
{
    const float* x    = (const float*)d_in[0];
    const float* ctxW = (const float*)d_in[1];
    const float* ctxb = (const float*)d_in[2];
    const float* qaW  = (const float*)d_in[3];
    const float* qab  = (const float*)d_in[4];
    const float* qbW  = (const float*)d_in[5];
    const float* qbb  = (const float*)d_in[6];
    const float* kaW  = (const float*)d_in[7];
    const float* kab  = (const float*)d_in[8];
    const float* kbW  = (const float*)d_in[9];
    const float* kbb  = (const float*)d_in[10];
    const float* vaW  = (const float*)d_in[11];
    const float* vab  = (const float*)d_in[12];
    const float* vbW  = (const float*)d_in[13];
    const float* vbb  = (const float*)d_in[14];
    const float* qeW  = (const float*)d_in[15];
    const float* qeb  = (const float*)d_in[16];
    const float* vqc  = (const float*)d_in[17];
    const float* ent  = (const float*)d_in[18];
    const float* outW = (const float*)d_in[19];
    const float* outb = (const float*)d_in[20];
    const float* gamma= (const float*)d_in[21];
    const float* beta = (const float*)d_in[22];
    float* out = (float*)d_out;

    // workspace layout (bytes, 256-aligned); ~73 MB
    char* p = (char*)d_ws;
    auto alloc = [&](size_t bytes) { char* r = p; p += (bytes + 255) & ~(size_t)255; return (void*)r; };
    ushort_t* xb    = (ushort_t*)alloc((size_t)BS * Ee * 2);          // 16.8 MB
    ushort_t* WcatT = (ushort_t*)alloc((size_t)NCAT * Ee * 2);        //  3.4 MB
    ushort_t* outWt = (ushort_t*)alloc((size_t)Ee * Ee * 2);          //  2.1 MB
    float*    bcat  = (float*)   alloc(NCAT * 4);
    ushort_t* Cf    = (ushort_t*)alloc((size_t)BS * NCAT * 2);        // 27.3 MB
    float*    qf    = (float*)   alloc((size_t)Bb*Hh*Ss*NF * 4);      //  8.4 MB
    float*    kf    = (float*)   alloc((size_t)Bb*KVh*Ss*NF * 4);     //  2.1 MB
    float*    vg    = (float*)   alloc((size_t)Bb*KVh*Ss*HD * 4);     //  8.4 MB
    float*    kvpart= (float*)   alloc((size_t)Bb*KVh*NC*NF*HD * 4);  //  4.2 MB
    float*    kfpart= (float*)   alloc((size_t)Bb*KVh*NC*NF * 4);
    ushort_t* obf   = Cf;                 // alias: Cf dead after combine_quantum
    ushort_t* obf2  = (ushort_t*)qf;      // alias: qf/kf/vg dead after attn_scan

    // 0) consolidated input cast + weight prep (one launch)
    prep_all<<<6759, 256, 0, stream>>>(x, xb, qaW, kaW, vaW, outW, ctxW,
                                       qab, kab, vab, ctxb, WcatT, outWt, bcat);

    // 1) fused projection GEMM: [8192,1024] @ [1024,1664] -> bf16
    gemm_mfma<0,1><<<dim3(NCAT/128, BS/128), 256, 0, stream>>>(
        xb, WcatT, bcat, nullptr, Cf, BS, NCAT, Ee);
    // 2+3) fused small-proj + TPA combine + quantum features
    combine_quantum<<<BS/4, 256, 0, stream>>>(Cf, qbW, qbb, kbW, kbb, vbW, vbb,
                                              qeW, qeb, vqc, ent, qf, kf, vg);
    // 4) causal linear attention: partials -> prefix -> scan (NC=64)
    chunk_partial<<<Bb*KVh*NC, 64, 0, stream>>>(kf, vg, kvpart, kfpart);
    prefix_scan<<<(Bb*KVh*(NF*HD + NF) + 255)/256, 256, 0, stream>>>(kvpart, kfpart);
    attn_scan<<<Bb*Hh*NC, 64, 0, stream>>>(qf, kf, vg, kvpart, kfpart, obf);
    // 5) out projection (bf16 out), then fused residual+LayerNorm
    gemm_mfma<0,1><<<dim3(Ee/128, BS/128), 256, 0, stream>>>(
        obf, outWt, outb, nullptr, obf2, BS, Ee, Ee);
    layernorm_res<<<BS, 256, 0, stream>>>(x, obf2, gamma, beta, out);
}

// Round 12
// 276.935 us; speedup vs baseline: 1.1398x; 1.0437x over previous
//
#include <hip/hip_runtime.h>
#include <math.h>

// Problem constants
#define Bb  4
#define Ss  2048
#define Ee  1024
#define Hh  16
#define KVh 4
#define HD  64
#define RNK 8
#define CDd 64
#define NQ  8
#define NLn 2
#define NF  16          // 2*NQ
#define NC  64          // chunks over S
#define CT  (Ss/NC)     // 32 steps per chunk
#define BS  (Bb*Ss)     // 8192 rows
#define NCAT 1664       // 512 qa + 512 ka + 512 va + 64 ctx + 64 pad

typedef unsigned short ushort_t;
typedef __attribute__((ext_vector_type(8))) short short8;
typedef __attribute__((ext_vector_type(4))) float f32x4;
typedef __attribute__((ext_vector_type(4))) unsigned short u16x4;

__device__ __forceinline__ unsigned short f2bf(float f) {
    unsigned int u = __float_as_uint(f);
    unsigned int r = (u + 0x7FFFu + ((u >> 16) & 1u)) >> 16;
    return (unsigned short)r;
}
__device__ __forceinline__ float bf2f(unsigned short h) {
    return __uint_as_float(((unsigned int)h) << 16);
}

#define GLD16(gp, lp) \
    __builtin_amdgcn_global_load_lds((const __attribute__((address_space(1))) void*)(gp), \
                                     (__attribute__((address_space(3))) void*)(lp), 16, 0, 0)

// ---------------- consolidated prep: x-cast + all weight transforms (one launch) ----
__global__ __launch_bounds__(256)
void prep_all(const float* __restrict__ x, ushort_t* __restrict__ xb,
              const float* __restrict__ qaW, const float* __restrict__ kaW,
              const float* __restrict__ vaW, const float* __restrict__ outW,
              const float* __restrict__ ctxW,
              const float* __restrict__ qab, const float* __restrict__ kab,
              const float* __restrict__ vab, const float* __restrict__ ctxb,
              ushort_t* __restrict__ WcatT, ushort_t* __restrict__ outWt,
              float* __restrict__ bcat)
{
    __shared__ float t[32][33];
    const int bid = blockIdx.x;
    const int tx = threadIdx.x & 31, ty = threadIdx.x >> 5;   // 32 x 8
    if (bid < 4096) {
        const long i = (long)bid * 2048 + threadIdx.x * 8;
        short8 o;
        #pragma unroll
        for (int j = 0; j < 8; ++j) o[j] = (short)f2bf(x[i + j]);
        *(short8*)(xb + i) = o;
    } else if (bid < 5632) {
        const int r0 = bid - 4096;
        const int z = r0 >> 9;               // 0..2
        const int r = r0 & 511;
        const int k0 = (r & 31) * 32, n0 = (r >> 5) * 32;
        const float* W = (z == 0) ? qaW : (z == 1) ? kaW : vaW;
        const int nOff = 512 * z;
        #pragma unroll
        for (int i = 0; i < 4; ++i)
            t[ty + 8*i][tx] = W[(size_t)(k0 + ty + 8*i) * 512 + (n0 + tx)];
        __syncthreads();
        #pragma unroll
        for (int i = 0; i < 4; ++i)
            WcatT[(size_t)(nOff + n0 + ty + 8*i) * Ee + (k0 + tx)] = f2bf(t[tx][ty + 8*i]);
    } else if (bid < 6656) {
        const int r = bid - 5632;
        const int k0 = (r & 31) * 32, n0 = (r >> 5) * 32;
        #pragma unroll
        for (int i = 0; i < 4; ++i)
            t[ty + 8*i][tx] = outW[(size_t)(k0 + ty + 8*i) * 1024 + (n0 + tx)];
        __syncthreads();
        #pragma unroll
        for (int i = 0; i < 4; ++i)
            outWt[(size_t)(n0 + ty + 8*i) * Ee + (k0 + tx)] = f2bf(t[tx][ty + 8*i]);
    } else {
        const int pid = bid - 6656;
        if (pid < 64) {
            const int k0 = (pid >> 1) * 32, n0 = (pid & 1) * 32;
            #pragma unroll
            for (int i = 0; i < 4; ++i)
                t[ty + 8*i][tx] = ctxW[(size_t)(k0 + ty + 8*i) * 64 + (n0 + tx)];
            __syncthreads();
            #pragma unroll
            for (int i = 0; i < 4; ++i)
                WcatT[(size_t)(1536 + n0 + ty + 8*i) * Ee + (k0 + tx)] = f2bf(t[tx][ty + 8*i]);
        } else if (pid < 96) {
            const int idx = (pid - 64) * 2048 + threadIdx.x * 8;
            short8 z = {0, 0, 0, 0, 0, 0, 0, 0};
            *(short8*)(WcatT + (size_t)1600 * Ee + idx) = z;
        } else {
            const int n = (pid - 96) * 256 + threadIdx.x;
            if (n < NCAT) {
                float v = 0.f;
                if      (n < 512)  v = qab[n];
                else if (n < 1024) v = kab[n - 512];
                else if (n < 1536) v = vab[n - 1024];
                else if (n < 1600) v = ctxb[n - 1536];
                bcat[n] = v;
            }
        }
    }
}

// ---------------- bf16 MFMA GEMM: C = A[M,K] @ Bt[N,K]^T + bias (+res) ----------------
// 128x128 tile, BK=32, 4 waves (2x2). T1 XCD swizzle.
// T3-minimum 2-phase — double-buffered LDS, stage tile t+1 before computing
// tile t, ONE barrier per iteration (its implicit vmcnt/lgkm drain is the sync).
template<int RES, int OUTBF>
__global__ __launch_bounds__(256)
void gemm_mfma(const ushort_t* __restrict__ A, const ushort_t* __restrict__ Bt,
               const float* __restrict__ bias, const float* __restrict__ res,
               void* __restrict__ Cout, int M, int N, int K)
{
    __shared__ ushort_t Al[2][128 * 32];
    __shared__ ushort_t Bl[2][128 * 32];
    const int tid  = threadIdx.x;
    const int lane = tid & 63;
    const int wave = tid >> 6;       // 0..3
    const int wm = wave >> 1;        // 0..1
    const int wn = wave & 1;         // 0..1

    // XCD-aware bijective swizzle
    const unsigned nx  = gridDim.x;
    const unsigned bid = blockIdx.y * nx + blockIdx.x;
    const unsigned nwg = nx * gridDim.y;
    const unsigned qc = nwg >> 3, rc = nwg & 7;
    const unsigned xc = bid & 7, of = bid >> 3;
    const unsigned tile = (xc < rc ? xc * (qc + 1) : rc * (qc + 1) + (xc - rc) * qc) + of;
    const int bm = (int)(tile / nx) * 128;
    const int bn = (int)(tile % nx) * 128;

    f32x4 acc[4][4] = {};            // [mi][ni]

    const int arow0 = wave * 16 + (lane >> 2);
    const int kq = lane & 3;
    const ushort_t* Ag0 = A  + (size_t)(bm + arow0) * K + kq * 8;
    const ushort_t* Ag1 = A  + (size_t)(bm + 64 + arow0) * K + kq * 8;
    const ushort_t* Bg0 = Bt + (size_t)(bn + arow0) * K + kq * 8;
    const ushort_t* Bg1 = Bt + (size_t)(bn + 64 + arow0) * K + kq * 8;

    const int fr = lane & 15;
    const int fg = lane >> 4;
    const int nt = K >> 5;

    // prologue: stage tile 0 into buffer 0
    {
        ushort_t* Aw = &Al[0][wave * 512];
        ushort_t* Bw = &Bl[0][wave * 512];
        GLD16(Ag0, Aw);
        GLD16(Ag1, Aw + 2048);
        GLD16(Bg0, Bw);
        GLD16(Bg1, Bw + 2048);
        __syncthreads();   // drains vmcnt -> tile 0 resident
    }

    for (int t = 0; t < nt; ++t) {
        const int cur = t & 1;
        // issue next-tile stage into the other buffer (in flight during MFMA)
        if (t + 1 < nt) {
            const int k1 = (t + 1) << 5;
            ushort_t* Aw = &Al[cur ^ 1][wave * 512];
            ushort_t* Bw = &Bl[cur ^ 1][wave * 512];
            GLD16(Ag0 + k1, Aw);
            GLD16(Ag1 + k1, Aw + 2048);
            GLD16(Bg0 + k1, Bw);
            GLD16(Bg1 + k1, Bw + 2048);
        }
        short8 af[4], bfv[4];
        #pragma unroll
        for (int mi = 0; mi < 4; ++mi)
            af[mi] = *(const short8*)&Al[cur][(wm*64 + mi*16 + fr) * 32 + fg * 8];
        #pragma unroll
        for (int ni = 0; ni < 4; ++ni)
            bfv[ni] = *(const short8*)&Bl[cur][(wn*64 + ni*16 + fr) * 32 + fg * 8];
        #pragma unroll
        for (int mi = 0; mi < 4; ++mi)
            #pragma unroll
            for (int ni = 0; ni < 4; ++ni)
                acc[mi][ni] = __builtin_amdgcn_mfma_f32_16x16x32_bf16(
                    af[mi], bfv[ni], acc[mi][ni], 0, 0, 0);
        __syncthreads();   // drains vmcnt (next tile landed) + lgkm (reads done)
    }

    // epilogue: C/D layout col=lane&15, row=(lane>>4)*4+reg  [HW-verified m89/m91]
    float bv[4];
    #pragma unroll
    for (int ni = 0; ni < 4; ++ni) bv[ni] = bias[bn + wn*64 + ni*16 + fr];
    #pragma unroll
    for (int mi = 0; mi < 4; ++mi) {
        #pragma unroll
        for (int ni = 0; ni < 4; ++ni) {
            const int gn = bn + wn*64 + ni*16 + fr;
            #pragma unroll
            for (int r = 0; r < 4; ++r) {
                const int gm = bm + wm*64 + mi*16 + fg*4 + r;
                float v = acc[mi][ni][r] + bv[ni];
                if (RES) v += res[(size_t)gm * N + gn];
                if (OUTBF) ((ushort_t*)Cout)[(size_t)gm * N + gn] = f2bf(v);
                else       ((float*)Cout)[(size_t)gm * N + gn] = v;
            }
        }
    }
}

// ---------------- fused small-proj + TPA combine + quantum features ----------------
// 256 threads = 4 waves; wave w handles (b,s) = blockIdx.x*4 + w; lane = dim d.
// 3-stripe fused angle-dot (shares qew loads), fast trig intrinsics.
__global__ __launch_bounds__(256)
void combine_quantum(const ushort_t* __restrict__ Cf,
                     const float* __restrict__ qbW, const float* __restrict__ qbb,
                     const float* __restrict__ kbW, const float* __restrict__ kbb,
                     const float* __restrict__ vbW, const float* __restrict__ vbb,
                     const float* __restrict__ qeW, const float* __restrict__ qeb,
                     const float* __restrict__ vqc, const float* __restrict__ ent,
                     float* __restrict__ qf_g, float* __restrict__ kf_g,
                     float* __restrict__ v_g)
{
    const int wid = threadIdx.x >> 6;   // 0..3 wave id
    const int d   = threadIdx.x & 63;   // lane
    const int bs  = blockIdx.x * 4 + wid;
    const int b = bs >> 11;             // S=2048
    const int s = bs & 2047;

    __shared__ float qew_s[HD*NQ];      // [dd*8+i]
    __shared__ float ctx_l[4][CDd];
    __shared__ float bfq[4][128];       // [r*16+h]
    __shared__ float bfk[4][32];        // [r*4+kvh]
    __shared__ float bfv[4][32];
    __shared__ float rows[4][Hh+KVh][65];

    #pragma unroll
    for (int i = 0; i < 2; ++i)
        qew_s[threadIdx.x + 256*i] = qeW[threadIdx.x + 256*i];

    const ushort_t* Crow = Cf + (size_t)bs * NCAT;
    ctx_l[wid][d] = bf2f(Crow[1536 + d]);
    __syncthreads();

    // cooperative small projections: thread t owns output column n for all 4 s
    {
        const int t = threadIdx.x;
        if (t < 192) {
            const float* Wc; float bb; int ldw;
            if (t < 128)      { Wc = qbW + t;         bb = qbb[t];       ldw = 128; }
            else if (t < 160) { Wc = kbW + (t - 128); bb = kbb[t - 128]; ldw = 32;  }
            else              { Wc = vbW + (t - 160); bb = vbb[t - 160]; ldw = 32;  }
            float a0 = bb, a1 = bb, a2 = bb, a3 = bb;
            #pragma unroll 8
            for (int k = 0; k < CDd; ++k) {
                const float w = Wc[(size_t)k * ldw];
                a0 += ctx_l[0][k] * w;
                a1 += ctx_l[1][k] * w;
                a2 += ctx_l[2][k] * w;
                a3 += ctx_l[3][k] * w;
            }
            if (t < 128) {
                bfq[0][t] = a0; bfq[1][t] = a1; bfq[2][t] = a2; bfq[3][t] = a3;
            } else if (t < 160) {
                const int n = t - 128;
                bfk[0][n] = a0; bfk[1][n] = a1; bfk[2][n] = a2; bfk[3][n] = a3;
            } else {
                const int n = t - 160;
                bfv[0][n] = a0; bfv[1][n] = a1; bfv[2][n] = a2; bfv[3][n] = a3;
            }
        }
    }

    // TPA A-factors: lane d owns dim d
    float aq[RNK], ak[RNK], av[RNK];
    #pragma unroll
    for (int r = 0; r < RNK; ++r) {
        aq[r] = bf2f(Crow[r*64 + d]);
        ak[r] = bf2f(Crow[512 + r*64 + d]);
        av[r] = bf2f(Crow[1024 + r*64 + d]);
    }
    __syncthreads();

    #pragma unroll
    for (int h = 0; h < Hh; ++h) {
        float acc = 0.f;
        #pragma unroll
        for (int r = 0; r < RNK; ++r) acc += aq[r] * bfq[wid][r*16 + h];
        rows[wid][h][d] = acc;
    }
    #pragma unroll
    for (int kvh = 0; kvh < KVh; ++kvh) {
        float acck = 0.f, accv = 0.f;
        #pragma unroll
        for (int r = 0; r < RNK; ++r) {
            acck += ak[r] * bfk[wid][r*4 + kvh];
            accv += av[r] * bfv[wid][r*4 + kvh];
        }
        rows[wid][Hh + kvh][d] = acck;
        v_g[((size_t)(b*KVh + kvh)*Ss + s)*HD + d] = accv;
    }
    __syncthreads();

    // ---- fused 3-stripe angle dots (shared qew load) + fast-trig VQC ----
    const float entv = ent[0];
    const int i   = d & 7;                       // qubit
    const int src = (d & ~7) | ((i + 7) & 7);    // lane of qubit i-1 (mod 8)
    const float p00 = vqc[(0*NQ + i)*3 + 0], p01 = vqc[(0*NQ + i)*3 + 1], p02 = vqc[(0*NQ + i)*3 + 2];
    const float p10 = vqc[(1*NQ + i)*3 + 0], p11 = vqc[(1*NQ + i)*3 + 1], p12 = vqc[(1*NQ + i)*3 + 2];
    const float qebi = qeb[i];
    const int r0 = d >> 3;                 // 0..7
    const int r1 = 8 + r0;                 // 8..15
    const bool act2 = (16 + r0) < (Hh + KVh);
    const int r2 = act2 ? (16 + r0) : (Hh + KVh - 1);

    float a0 = qebi, a1 = qebi, a2 = qebi;
    #pragma unroll 8
    for (int dd = 0; dd < HD; ++dd) {
        const float qw = qew_s[dd*8 + i];
        a0 += rows[wid][r0][dd] * qw;
        a1 += rows[wid][r1][dd] * qw;
        a2 += rows[wid][r2][dd] * qw;
    }

    float accs[3] = {a0, a1, a2};
    const int rowNo[3] = {r0, r1, 16 + r0};
    const bool activ[3] = {true, true, act2};
    #pragma unroll
    for (int stripe = 0; stripe < 3; ++stripe) {
        float acc = fminf(fmaxf(accs[stripe], -15.f), 15.f);
        const float e = __expf(2.f * acc);
        float f = ((e - 1.f) / (e + 1.f)) * 3.14159265358979323846f;
        // layer 0
        float g = __cosf(f + p00) * __sinf(f + p01) + __cosf(f + p02);
        float gp = __shfl(g, src, 64);
        f = g * (1.f + entv * gp);
        // layer 1
        g = __cosf(f + p10) * __sinf(f + p11) + __cosf(f + p12);
        gp = __shfl(g, src, 64);
        f = g * (1.f + entv * gp);
        // features + 8-group norm
        const float c = __cosf(f), sn = __sinf(f);
        float ss = c*c + sn*sn;
        ss += __shfl_xor(ss, 1, 64);
        ss += __shfl_xor(ss, 2, 64);
        ss += __shfl_xor(ss, 4, 64);
        const float inv = 1.f / (sqrtf(ss) + 1e-6f);
        if (activ[stripe]) {
            const int row = rowNo[stripe];
            float* dst = (row < Hh)
                ? qf_g + ((size_t)(b*Hh + row)*Ss + s)*NF
                : kf_g + ((size_t)(b*KVh + (row - Hh))*Ss + s)*NF;
            dst[i]      = c * inv;
            dst[NQ + i] = sn * inv;
        }
    }
}

// ---------------- chunk partial KV state sums, per (b,kvh,chunk) ----------------
__global__ __launch_bounds__(64)
void chunk_partial(const float* __restrict__ kf_g, const float* __restrict__ v_g,
                   float* __restrict__ kvpart, float* __restrict__ kfpart)
{
    const int id = blockIdx.x;
    const int c = id & (NC-1);
    const int bk = id / NC;
    const int d = threadIdx.x;
    __shared__ float kf_l[CT][NF];
    const int s0 = c * CT;
    const float* kfp = kf_g + ((size_t)bk*Ss + s0)*NF;
    #pragma unroll
    for (int t = 0; t < (CT*NF)/64; ++t)
        ((float*)kf_l)[d + 64*t] = kfp[d + 64*t];
    __syncthreads();
    float st[NF] = {};
    const float* vp = v_g + ((size_t)bk*Ss + s0)*HD;
    for (int t = 0; t < CT; ++t) {
        const float vd = vp[(size_t)t*HD + d];
        #pragma unroll
        for (int f = 0; f < NF; ++f) st[f] += kf_l[t][f] * vd;
    }
    float* kvp = kvpart + (size_t)id * (NF*HD);
    #pragma unroll
    for (int f = 0; f < NF; ++f) kvp[f*HD + d] = st[f];
    if (d < NF) {
        float acc = 0.f;
        for (int t = 0; t < CT; ++t) acc += kf_l[t][d];
        kfpart[(size_t)id*NF + d] = acc;
    }
}

// ---------------- exclusive prefix over chunks (in-place) ----------------
__global__ void prefix_scan(float* __restrict__ kvpart, float* __restrict__ kfpart)
{
    const int idx = blockIdx.x * blockDim.x + threadIdx.x;
    const int total = Bb*KVh * (NF*HD + NF);
    if (idx >= total) return;
    const int bk = idx / (NF*HD + NF);
    const int e = idx % (NF*HD + NF);
    if (e < NF*HD) {
        float* p = kvpart + (size_t)bk*NC*(NF*HD) + e;
        float run = 0.f;
        for (int c = 0; c < NC; ++c) {
            const float t = p[(size_t)c*(NF*HD)];
            p[(size_t)c*(NF*HD)] = run;
            run += t;
        }
    } else {
        const int f = e - NF*HD;
        float* p = kfpart + (size_t)bk*NC*NF + f;
        float run = 0.f;
        for (int c = 0; c < NC; ++c) {
            const float t = p[(size_t)c*NF];
            p[(size_t)c*NF] = run;
            run += t;
        }
    }
}

// ---------------- attention scan, per (b,h,chunk); writes bf16 o ----------------
__global__ __launch_bounds__(64)
void attn_scan(const float* __restrict__ qf_g, const float* __restrict__ kf_g,
               const float* __restrict__ v_g,
               const float* __restrict__ kvpart, const float* __restrict__ kfpart,
               ushort_t* __restrict__ o_bf)
{
    const int id = blockIdx.x;
    const int c = id & (NC-1);
    const int bh = id / NC;
    const int h = bh & (Hh-1);
    const int b = bh / Hh;
    const int kvh = h >> 2;
    const int d = threadIdx.x;
    __shared__ float kf_l[CT][NF];
    __shared__ float qf_l[CT][NF];
    const int s0 = c * CT;
    const float* kfp = kf_g + ((size_t)(b*KVh + kvh)*Ss + s0)*NF;
    const float* qfp = qf_g + ((size_t)(b*Hh + h)*Ss + s0)*NF;
    #pragma unroll
    for (int t = 0; t < (CT*NF)/64; ++t) {
        ((float*)kf_l)[d + 64*t] = kfp[d + 64*t];
        ((float*)qf_l)[d + 64*t] = qfp[d + 64*t];
    }
    float st[NF], kfs[NF];
    const float* kvp  = kvpart + ((size_t)(b*KVh + kvh)*NC + c)*(NF*HD);
    const float* kfsp = kfpart + ((size_t)(b*KVh + kvh)*NC + c)*NF;
    #pragma unroll
    for (int f = 0; f < NF; ++f) { st[f] = kvp[f*HD + d]; kfs[f] = kfsp[f]; }
    __syncthreads();
    const float* vp = v_g + ((size_t)(b*KVh + kvh)*Ss + s0)*HD;
    ushort_t* op = o_bf + ((size_t)(b*Ss + s0))*Ee + h*HD;
    for (int t = 0; t < CT; ++t) {
        const float vd = vp[(size_t)t*HD + d];
        float num0 = 0.f, num1 = 0.f, den0 = 0.f, den1 = 0.f;
        #pragma unroll
        for (int f = 0; f < NF; f += 2) {
            const float kv0 = kf_l[t][f];
            const float kv1 = kf_l[t][f+1];
            st[f]   += kv0 * vd;   kfs[f]   += kv0;
            st[f+1] += kv1 * vd;   kfs[f+1] += kv1;
            const float qv0 = qf_l[t][f];
            const float qv1 = qf_l[t][f+1];
            num0 += qv0 * st[f];   den0 += qv0 * kfs[f];
            num1 += qv1 * st[f+1]; den1 += qv1 * kfs[f+1];
        }
        op[(size_t)t*Ee + d] = f2bf((num0 + num1) / ((den0 + den1) + 1e-6f));
    }
}

// ---------------- residual + LayerNorm: out = LN(x + o_bf16), vectorized ----------------
__global__ __launch_bounds__(256)
void layernorm_res(const float* __restrict__ x, const ushort_t* __restrict__ o_bf,
                   const float* __restrict__ gamma, const float* __restrict__ beta,
                   float* __restrict__ out)
{
    __shared__ float tmp[4];
    const int row = blockIdx.x;
    const int t = threadIdx.x;
    const float* xp = x + (size_t)row * Ee;
    const ushort_t* op = o_bf + (size_t)row * Ee;
    const f32x4 xv = *(const f32x4*)(xp + t*4);
    const u16x4 ov = *(const u16x4*)(op + t*4);
    float v[4];
    float sum = 0.f;
    #pragma unroll
    for (int i = 0; i < 4; ++i) { v[i] = xv[i] + bf2f(ov[i]); sum += v[i]; }
    #pragma unroll
    for (int o = 32; o > 0; o >>= 1) sum += __shfl_down(sum, o, 64);
    if ((t & 63) == 0) tmp[t >> 6] = sum;
    __syncthreads();
    const float mu = (tmp[0] + tmp[1] + tmp[2] + tmp[3]) * (1.f/Ee);
    __syncthreads();
    float vs = 0.f;
    #pragma unroll
    for (int i = 0; i < 4; ++i) { const float dd = v[i] - mu; vs += dd*dd; }
    #pragma unroll
    for (int o = 32; o > 0; o >>= 1) vs += __shfl_down(vs, o, 64);
    if ((t & 63) == 0) tmp[t >> 6] = vs;
    __syncthreads();
    const float var = (tmp[0] + tmp[1] + tmp[2] + tmp[3]) * (1.f/Ee);
    const float inv = rsqrtf(var + 1e-5f);
    const f32x4 gv = *(const f32x4*)(gamma + t*4);
    const f32x4 bv = *(const f32x4*)(beta + t*4);
    f32x4 ovec;
    #pragma unroll
    for (int i = 0; i < 4; ++i) ovec[i] = gv[i] * (v[i] - mu) * inv + bv[i];
    *(f32x4*)(out + (size_t)row * Ee + t*4) = ovec;
}

extern "C" void kernel_launch(void* const* d_in, const int* in_sizes, int n_in,
                              void* d_out, int out_size, void* d_ws, size_t ws_size,
                              hipStream_t stream)
{
    const float* x    = (const float*)d_in[0];
    const float* ctxW = (const float*)d_in[1];
    const float* ctxb = (const float*)d_in[2];
    const float* qaW  = (const float*)d_in[3];
    const float* qab  = (const float*)d_in[4];
    const float* qbW  = (const float*)d_in[5];
    const float* qbb  = (const float*)d_in[6];
    const float* kaW  = (const float*)d_in[7];
    const float* kab  = (const float*)d_in[8];
    const float* kbW  = (const float*)d_in[9];
    const float* kbb  = (const float*)d_in[10];
    const float* vaW  = (const float*)d_in[11];
    const float* vab  = (const float*)d_in[12];
    const float* vbW  = (const float*)d_in[13];
    const float* vbb  = (const float*)d_in[14];
    const float* qeW  = (const float*)d_in[15];
    const float* qeb  = (const float*)d_in[16];
    const float* vqc  = (const float*)d_in[17];
    const float* ent  = (const float*)d_in[18];
    const float* outW = (const float*)d_in[19];
    const float* outb = (const float*)d_in[20];
    const float* gamma= (const float*)d_in[21];
    const float* beta = (const float*)d_in[22];
    float* out = (float*)d_out;

    // workspace layout (bytes, 256-aligned); ~73 MB
    char* p = (char*)d_ws;
    auto alloc = [&](size_t bytes) { char* r = p; p += (bytes + 255) & ~(size_t)255; return (void*)r; };
    ushort_t* xb    = (ushort_t*)alloc((size_t)BS * Ee * 2);          // 16.8 MB
    ushort_t* WcatT = (ushort_t*)alloc((size_t)NCAT * Ee * 2);        //  3.4 MB
    ushort_t* outWt = (ushort_t*)alloc((size_t)Ee * Ee * 2);          //  2.1 MB
    float*    bcat  = (float*)   alloc(NCAT * 4);
    ushort_t* Cf    = (ushort_t*)alloc((size_t)BS * NCAT * 2);        // 27.3 MB
    float*    qf    = (float*)   alloc((size_t)Bb*Hh*Ss*NF * 4);      //  8.4 MB
    float*    kf    = (float*)   alloc((size_t)Bb*KVh*Ss*NF * 4);     //  2.1 MB
    float*    vg    = (float*)   alloc((size_t)Bb*KVh*Ss*HD * 4);     //  8.4 MB
    float*    kvpart= (float*)   alloc((size_t)Bb*KVh*NC*NF*HD * 4);  //  4.2 MB
    float*    kfpart= (float*)   alloc((size_t)Bb*KVh*NC*NF * 4);
    ushort_t* obf   = Cf;                 // alias: Cf dead after combine_quantum
    ushort_t* obf2  = (ushort_t*)qf;      // alias: qf/kf/vg dead after attn_scan

    // 0) consolidated input cast + weight prep (one launch)
    prep_all<<<6759, 256, 0, stream>>>(x, xb, qaW, kaW, vaW, outW, ctxW,
                                       qab, kab, vab, ctxb, WcatT, outWt, bcat);

    // 1) fused projection GEMM: [8192,1024] @ [1024,1664] -> bf16
    gemm_mfma<0,1><<<dim3(NCAT/128, BS/128), 256, 0, stream>>>(
        xb, WcatT, bcat, nullptr, Cf, BS, NCAT, Ee);
    // 2+3) fused small-proj + TPA combine + quantum features
    combine_quantum<<<BS/4, 256, 0, stream>>>(Cf, qbW, qbb, kbW, kbb, vbW, vbb,
                                              qeW, qeb, vqc, ent, qf, kf, vg);
    // 4) causal linear attention: partials -> prefix -> scan (NC=64)
    chunk_partial<<<Bb*KVh*NC, 64, 0, stream>>>(kf, vg, kvpart, kfpart);
    prefix_scan<<<(Bb*KVh*(NF*HD + NF) + 255)/256, 256, 0, stream>>>(kvpart, kfpart);
    attn_scan<<<Bb*Hh*NC, 64, 0, stream>>>(qf, kf, vg, kvpart, kfpart, obf);
    // 5) out projection (bf16 out), then fused residual+LayerNorm
    gemm_mfma<0,1><<<dim3(Ee/128, BS/128), 256, 0, stream>>>(
        obf, outWt, outb, nullptr, obf2, BS, Ee, Ee);
    layernorm_res<<<BS, 256, 0, stream>>>(x, obf2, gamma, beta, out);
}